// Round 1
// baseline (3939.806 us; speedup 1.0000x reference)
//
#include <hip/hip_runtime.h>

// Problem constants (fixed by the reference)
#define NN 100000   // nodes
#define EE 500000   // edges per relation
#define RR 3        // relations
#define LL 2        // layers
#define FF 300      // input features
#define HH 256      // hidden
#define CC 23       // classes

static inline int cdiv_h(int a, int b) { return (a + b - 1) / b; }

// ---------------------------------------------------------------------------
// Degree histogram: counts per relation for src (out-degree) and dst (in-deg)
// ---------------------------------------------------------------------------
__global__ void hist_kernel(const int* __restrict__ src, const int* __restrict__ dst,
                            int* __restrict__ cnt_out, int* __restrict__ cnt_in,
                            int RE, int Eper) {
    int i = blockIdx.x * blockDim.x + threadIdx.x;
    if (i >= RE) return;
    int r = i / Eper;
    atomicAdd(&cnt_out[r * NN + src[i]], 1);
    atomicAdd(&cnt_in[r * NN + dst[i]], 1);
}

// rs = rsqrt(max(deg,1))
__global__ void rs_kernel(const int* __restrict__ cnt_out, const int* __restrict__ cnt_in,
                          float* __restrict__ rs_out, float* __restrict__ rs_in, int total) {
    int i = blockIdx.x * blockDim.x + threadIdx.x;
    if (i >= total) return;
    rs_out[i] = rsqrtf(fmaxf((float)cnt_out[i], 1.0f));
    rs_in[i]  = rsqrtf(fmaxf((float)cnt_in[i], 1.0f));
}

// ---------------------------------------------------------------------------
// Exclusive scan of in-degree counts -> CSR offsets. One block per relation.
// ---------------------------------------------------------------------------
__global__ __launch_bounds__(1024) void scan_kernel(const int* __restrict__ cnt_in,
                                                    int* __restrict__ offs) {
    int r = blockIdx.x;
    const int* cnt = cnt_in + r * NN;
    int* off = offs + (size_t)r * (NN + 1);
    int t = threadIdx.x;
    const int chunk = (NN + 1023) / 1024;  // 98
    int lo = t * chunk;
    int hi = lo + chunk; if (hi > NN) hi = NN; if (lo > NN) lo = NN;
    int s = 0;
    for (int i = lo; i < hi; i++) s += cnt[i];
    __shared__ int sh[1024];
    sh[t] = s;
    __syncthreads();
    for (int d = 1; d < 1024; d <<= 1) {
        int v = (t >= d) ? sh[t - d] : 0;
        __syncthreads();
        sh[t] += v;
        __syncthreads();
    }
    int run = sh[t] - s;  // exclusive prefix
    for (int i = lo; i < hi; i++) { off[i] = run; run += cnt[i]; }
    if (t == 1023) off[NN] = sh[1023];
}

__global__ void cursor_init(const int* __restrict__ offs, int* __restrict__ cur, int total) {
    int i = blockIdx.x * blockDim.x + threadIdx.x;
    if (i >= total) return;
    int r = i / NN;
    int n = i - r * NN;
    cur[i] = offs[(size_t)r * (NN + 1) + n];
}

// Fill CSR src lists (order within a bucket is arbitrary -> fp32 reorder only)
__global__ void fill_kernel(const int* __restrict__ src, const int* __restrict__ dst,
                            int* __restrict__ cur, int* __restrict__ srcs,
                            int RE, int Eper) {
    int i = blockIdx.x * blockDim.x + threadIdx.x;
    if (i >= RE) return;
    int r = i / Eper;
    int d = dst[i];
    int pos = atomicAdd(&cur[r * NN + d], 1);
    srcs[(size_t)r * Eper + pos] = src[i];
}

// ---------------------------------------------------------------------------
// Aggregation: one wave (64 lanes) per dst node, 4 floats per lane (H=256).
// m[dst] = rs_in[dst] * sum_{e: dst} rs_out[src] * h[src]
// ---------------------------------------------------------------------------
__global__ __launch_bounds__(256) void agg_kernel(const float* __restrict__ h,
                                                  const int* __restrict__ offs,
                                                  const int* __restrict__ srcs,
                                                  const float* __restrict__ rs_out,
                                                  const float* __restrict__ rs_in,
                                                  float* __restrict__ m) {
    int wave = threadIdx.x >> 6;
    int lane = threadIdx.x & 63;
    int node = blockIdx.x * 4 + wave;
    if (node >= NN) return;
    int s0 = offs[node], s1 = offs[node + 1];
    float4 acc = make_float4(0.f, 0.f, 0.f, 0.f);
    for (int k = s0; k < s1; k++) {
        int s = srcs[k];
        float w = rs_out[s];
        float4 hv = *(const float4*)(h + (size_t)s * HH + lane * 4);
        acc.x += w * hv.x; acc.y += w * hv.y; acc.z += w * hv.z; acc.w += w * hv.w;
    }
    float wi = rs_in[node];
    acc.x *= wi; acc.y *= wi; acc.z *= wi; acc.w *= wi;
    *(float4*)(m + (size_t)node * HH + lane * 4) = acc;
}

// ---------------------------------------------------------------------------
// SGEMM: C[M,Nc] (+)= alpha * (A[M,K] @ B[K,Nc] + bias[Nc])
// 128x128 tile, BK=8, 256 threads, 8x8 microtile.
// ---------------------------------------------------------------------------
__global__ __launch_bounds__(256) void sgemm(const float* __restrict__ A,
                                             const float* __restrict__ B,
                                             const float* __restrict__ bias,
                                             float* __restrict__ C,
                                             int M, int K, int Nc,
                                             float alpha, int accumulate) {
    __shared__ float As[8][128];
    __shared__ float Bs[8][128];
    int tid = threadIdx.x;
    int bm = blockIdx.y * 128;
    int bn = blockIdx.x * 128;
    int tx = tid & 15;       // 0..15 -> column group
    int ty = tid >> 4;       // 0..15 -> row group
    int arow = tid >> 1, acol = (tid & 1) * 4;   // A tile load: 128 rows x 8 k
    int brow = tid >> 5, bcol = (tid & 31) * 4;  // B tile load: 8 k x 128 cols

    float acc[8][8];
#pragma unroll
    for (int i = 0; i < 8; i++)
#pragma unroll
        for (int j = 0; j < 8; j++) acc[i][j] = 0.f;

    for (int k0 = 0; k0 < K; k0 += 8) {
        // Load A tile
        float4 av = make_float4(0.f, 0.f, 0.f, 0.f);
        int garow = bm + arow;
        if (garow < M) {
            if (k0 + acol + 3 < K) {
                av = *(const float4*)(A + (size_t)garow * K + k0 + acol);
            } else {
                float t0 = 0.f, t1 = 0.f, t2 = 0.f, t3 = 0.f;
                int kk = k0 + acol;
                if (kk + 0 < K) t0 = A[(size_t)garow * K + kk + 0];
                if (kk + 1 < K) t1 = A[(size_t)garow * K + kk + 1];
                if (kk + 2 < K) t2 = A[(size_t)garow * K + kk + 2];
                if (kk + 3 < K) t3 = A[(size_t)garow * K + kk + 3];
                av = make_float4(t0, t1, t2, t3);
            }
        }
        As[acol + 0][arow] = av.x;
        As[acol + 1][arow] = av.y;
        As[acol + 2][arow] = av.z;
        As[acol + 3][arow] = av.w;
        // Load B tile
        float4 bv = make_float4(0.f, 0.f, 0.f, 0.f);
        int gbrow = k0 + brow;
        if (gbrow < K) {
            if (bn + bcol + 3 < Nc) {
                bv = *(const float4*)(B + (size_t)gbrow * Nc + bn + bcol);
            } else {
                float t0 = 0.f, t1 = 0.f, t2 = 0.f, t3 = 0.f;
                int nn = bn + bcol;
                if (nn + 0 < Nc) t0 = B[(size_t)gbrow * Nc + nn + 0];
                if (nn + 1 < Nc) t1 = B[(size_t)gbrow * Nc + nn + 1];
                if (nn + 2 < Nc) t2 = B[(size_t)gbrow * Nc + nn + 2];
                if (nn + 3 < Nc) t3 = B[(size_t)gbrow * Nc + nn + 3];
                bv = make_float4(t0, t1, t2, t3);
            }
        }
        *(float4*)&Bs[brow][bcol] = bv;
        __syncthreads();
#pragma unroll
        for (int kk = 0; kk < 8; kk++) {
            float4 a0 = *(const float4*)&As[kk][ty * 8];
            float4 a1 = *(const float4*)&As[kk][ty * 8 + 4];
            float4 b0 = *(const float4*)&Bs[kk][tx * 8];
            float4 b1 = *(const float4*)&Bs[kk][tx * 8 + 4];
            float a[8] = {a0.x, a0.y, a0.z, a0.w, a1.x, a1.y, a1.z, a1.w};
            float b[8] = {b0.x, b0.y, b0.z, b0.w, b1.x, b1.y, b1.z, b1.w};
#pragma unroll
            for (int i = 0; i < 8; i++)
#pragma unroll
                for (int j = 0; j < 8; j++) acc[i][j] += a[i] * b[j];
        }
        __syncthreads();
    }
    // Epilogue
#pragma unroll
    for (int i = 0; i < 8; i++) {
        int row = bm + ty * 8 + i;
        if (row >= M) continue;
#pragma unroll
        for (int j = 0; j < 8; j++) {
            int col = bn + tx * 8 + j;
            if (col >= Nc) continue;
            float v = acc[i][j] + (bias ? bias[col] : 0.f);
            v *= alpha;
            size_t idx = (size_t)row * Nc + col;
            C[idx] = accumulate ? (C[idx] + v) : v;
        }
    }
}

// ---------------------------------------------------------------------------
// BN column stats: sum and sumsq per column (H=256 columns)
// ---------------------------------------------------------------------------
__global__ __launch_bounds__(256) void bn_stats(const float* __restrict__ Z,
                                                float* __restrict__ stats, int M) {
    int col = threadIdx.x;
    int r0 = blockIdx.x * 128;
    int rend = r0 + 128; if (rend > M) rend = M;
    float s = 0.f, s2 = 0.f;
    for (int r = r0; r < rend; r++) {
        float v = Z[(size_t)r * HH + col];
        s += v; s2 += v * v;
    }
    atomicAdd(&stats[col], s);
    atomicAdd(&stats[HH + col], s2);
}

// act: 0 = none, 1 = relu, 2 = leaky relu (0.01)
__global__ __launch_bounds__(256) void bn_apply(const float* __restrict__ Z,
                                                const float* __restrict__ stats,
                                                const float* __restrict__ g,
                                                const float* __restrict__ b,
                                                float* __restrict__ Out,
                                                int total, int act, float invM) {
    int idx = blockIdx.x * blockDim.x + threadIdx.x;
    if (idx >= total) return;
    int col = idx & (HH - 1);
    float mean = stats[col] * invM;
    float var = stats[HH + col] * invM - mean * mean;
    float inv = rsqrtf(var + 1e-5f);
    float v = (Z[idx] - mean) * inv * g[col] + b[col];
    if (act == 1) v = fmaxf(v, 0.f);
    else if (act == 2) v = (v < 0.f) ? 0.01f * v : v;
    Out[idx] = v;
}

// ---------------------------------------------------------------------------
extern "C" void kernel_launch(void* const* d_in, const int* in_sizes, int n_in,
                              void* d_out, int out_size, void* d_ws, size_t ws_size,
                              hipStream_t stream) {
    const float* x        = (const float*)d_in[0];
    const int*   esrc     = (const int*)d_in[1];
    const int*   edst     = (const int*)d_in[2];
    const float* W_feat   = (const float*)d_in[3];
    const float* b_feat   = (const float*)d_in[4];
    const float* g_feat   = (const float*)d_in[5];
    const float* beta_feat= (const float*)d_in[6];
    const float* gcn_W    = (const float*)d_in[7];
    const float* gcn_b    = (const float*)d_in[8];
    const float* skip_W   = (const float*)d_in[9];
    const float* skip_b   = (const float*)d_in[10];
    const float* bn_g     = (const float*)d_in[11];
    const float* bn_b     = (const float*)d_in[12];
    const float* W_c1     = (const float*)d_in[13];
    const float* b_c1     = (const float*)d_in[14];
    const float* g_c      = (const float*)d_in[15];
    const float* beta_c   = (const float*)d_in[16];
    const float* W_c2     = (const float*)d_in[17];
    const float* b_c2     = (const float*)d_in[18];
    float* out = (float*)d_out;

    // Workspace layout
    const size_t NH = (size_t)NN * HH;  // 25.6M floats
    char* w = (char*)d_ws;
    size_t off = 0;
    float* f_h   = (float*)(w + off); off += NH * 4;
    float* f_m   = (float*)(w + off); off += NH * 4;
    float* f_acc = (float*)(w + off); off += NH * 4;
    float* f_stats = (float*)(w + off); off += 2 * HH * 4;
    float* f_rs_out = (float*)(w + off); off += (size_t)RR * NN * 4;
    float* f_rs_in  = (float*)(w + off); off += (size_t)RR * NN * 4;
    int* i_cnt_out = (int*)(w + off); off += (size_t)RR * NN * 4;
    int* i_cnt_in  = (int*)(w + off); off += (size_t)RR * NN * 4;
    int* i_off = (int*)(w + off); off += (size_t)(RR * (NN + 1) + 13) * 4; // pad to 16B
    int* i_cur = (int*)(w + off); off += (size_t)RR * NN * 4;
    int* i_srcs = (int*)(w + off); off += (size_t)RR * EE * 4;
    (void)ws_size; (void)in_sizes; (void)n_in; (void)out_size;

    const float invM = 1.0f / (float)NN;
    const int RE = RR * EE;

    // --- CSR + degrees (edge structure is fixed per launch) ---
    hipMemsetAsync(i_cnt_out, 0, 2 * (size_t)RR * NN * 4, stream);  // cnt_out + cnt_in adjacent
    hist_kernel<<<cdiv_h(RE, 256), 256, 0, stream>>>(esrc, edst, i_cnt_out, i_cnt_in, RE, EE);
    rs_kernel<<<cdiv_h(RR * NN, 256), 256, 0, stream>>>(i_cnt_out, i_cnt_in, f_rs_out, f_rs_in, RR * NN);
    scan_kernel<<<RR, 1024, 0, stream>>>(i_cnt_in, i_off);
    cursor_init<<<cdiv_h(RR * NN, 256), 256, 0, stream>>>(i_off, i_cur, RR * NN);
    fill_kernel<<<cdiv_h(RE, 256), 256, 0, stream>>>(esrc, edst, i_cur, i_srcs, RE, EE);

    dim3 gemm_grid_H(cdiv_h(HH, 128), cdiv_h(NN, 128));
    dim3 gemm_grid_C(cdiv_h(CC, 128), cdiv_h(NN, 128));

    // --- feat_reduce: h = relu(BN(x @ W_feat + b_feat)) ---
    sgemm<<<gemm_grid_H, 256, 0, stream>>>(x, W_feat, b_feat, f_acc, NN, FF, HH, 1.0f, 0);
    hipMemsetAsync(f_stats, 0, 2 * HH * 4, stream);
    bn_stats<<<cdiv_h(NN, 128), 256, 0, stream>>>(f_acc, f_stats, NN);
    bn_apply<<<cdiv_h((int)NH, 256), 256, 0, stream>>>(f_acc, f_stats, g_feat, beta_feat, f_h,
                                                       (int)NH, 1, invM);

    // --- GCN layers ---
    for (int l = 0; l < LL; l++) {
        // acc = h @ skip_W[l] + skip_b[l]
        sgemm<<<gemm_grid_H, 256, 0, stream>>>(f_h, skip_W + (size_t)l * HH * HH,
                                               skip_b + (size_t)l * HH, f_acc, NN, HH, HH, 1.0f, 0);
        for (int r = 0; r < RR; r++) {
            agg_kernel<<<cdiv_h(NN, 4), 256, 0, stream>>>(
                f_h, i_off + (size_t)r * (NN + 1), i_srcs + (size_t)r * EE,
                f_rs_out + (size_t)r * NN, f_rs_in + (size_t)r * NN, f_m);
            // acc += (1/3) * (m @ gcn_W[l,r] + gcn_b[l,r])
            sgemm<<<gemm_grid_H, 256, 0, stream>>>(
                f_m, gcn_W + ((size_t)(l * RR + r)) * HH * HH,
                gcn_b + ((size_t)(l * RR + r)) * HH, f_acc, NN, HH, HH, 1.0f / 3.0f, 1);
        }
        hipMemsetAsync(f_stats, 0, 2 * HH * 4, stream);
        bn_stats<<<cdiv_h(NN, 128), 256, 0, stream>>>(f_acc, f_stats, NN);
        bn_apply<<<cdiv_h((int)NH, 256), 256, 0, stream>>>(f_acc, f_stats, bn_g + (size_t)l * HH,
                                                           bn_b + (size_t)l * HH, f_h, (int)NH, 2, invM);
    }

    // --- head: out = relu(BN(h @ W_c1 + b_c1)) @ W_c2 + b_c2 ---
    sgemm<<<gemm_grid_H, 256, 0, stream>>>(f_h, W_c1, b_c1, f_m, NN, HH, HH, 1.0f, 0);
    hipMemsetAsync(f_stats, 0, 2 * HH * 4, stream);
    bn_stats<<<cdiv_h(NN, 128), 256, 0, stream>>>(f_m, f_stats, NN);
    bn_apply<<<cdiv_h((int)NH, 256), 256, 0, stream>>>(f_m, f_stats, g_c, beta_c, f_m, (int)NH, 1, invM);
    sgemm<<<gemm_grid_C, 256, 0, stream>>>(f_m, W_c2, b_c2, out, NN, HH, CC, 1.0f, 0);
}

// Round 2
// 1856.818 us; speedup vs baseline: 2.1218x; 2.1218x over previous
//
#include <hip/hip_runtime.h>

#define NN 100000   // nodes
#define EE 500000   // edges per relation
#define RR 3        // relations
#define LL 2        // layers
#define FF 300      // input features
#define HH 256      // hidden
#define CC 23       // classes
#define MPAD 100096 // 782 * 128

static inline int cdiv_h(int a, int b) { return (a + b - 1) / b; }

typedef __attribute__((ext_vector_type(8))) short bf16x8;
typedef __attribute__((ext_vector_type(4))) float f32x4;

__device__ inline unsigned short f2bf(float f) {
    union { float f; unsigned int u; } v; v.f = f;
    unsigned int r = v.u + 0x7fff + ((v.u >> 16) & 1);
    return (unsigned short)(r >> 16);
}
__device__ inline float bf2f(unsigned short u) {
    union { unsigned int u; float f; } v; v.u = ((unsigned int)u) << 16;
    return v.f;
}
__device__ inline void gl_lds16(const void* g, void* l) {
    __builtin_amdgcn_global_load_lds((const __attribute__((address_space(1))) unsigned int*)g,
                                     (__attribute__((address_space(3))) unsigned int*)l,
                                     16, 0, 0);
}

// ---------------------------------------------------------------------------
// CSR build (unchanged from passing round)
// ---------------------------------------------------------------------------
__global__ void hist_kernel(const int* __restrict__ src, const int* __restrict__ dst,
                            int* __restrict__ cnt_out, int* __restrict__ cnt_in,
                            int RE, int Eper) {
    int i = blockIdx.x * blockDim.x + threadIdx.x;
    if (i >= RE) return;
    int r = i / Eper;
    atomicAdd(&cnt_out[r * NN + src[i]], 1);
    atomicAdd(&cnt_in[r * NN + dst[i]], 1);
}

__global__ void rs_kernel(const int* __restrict__ cnt_out, const int* __restrict__ cnt_in,
                          float* __restrict__ rs_out, float* __restrict__ rs_in, int total) {
    int i = blockIdx.x * blockDim.x + threadIdx.x;
    if (i >= total) return;
    rs_out[i] = rsqrtf(fmaxf((float)cnt_out[i], 1.0f));
    rs_in[i]  = rsqrtf(fmaxf((float)cnt_in[i], 1.0f));
}

__global__ __launch_bounds__(1024) void scan_kernel(const int* __restrict__ cnt_in,
                                                    int* __restrict__ offs) {
    int r = blockIdx.x;
    const int* cnt = cnt_in + r * NN;
    int* off = offs + (size_t)r * (NN + 1);
    int t = threadIdx.x;
    const int chunk = (NN + 1023) / 1024;
    int lo = t * chunk;
    int hi = lo + chunk; if (hi > NN) hi = NN; if (lo > NN) lo = NN;
    int s = 0;
    for (int i = lo; i < hi; i++) s += cnt[i];
    __shared__ int sh[1024];
    sh[t] = s;
    __syncthreads();
    for (int d = 1; d < 1024; d <<= 1) {
        int v = (t >= d) ? sh[t - d] : 0;
        __syncthreads();
        sh[t] += v;
        __syncthreads();
    }
    int run = sh[t] - s;
    for (int i = lo; i < hi; i++) { off[i] = run; run += cnt[i]; }
    if (t == 1023) off[NN] = sh[1023];
}

__global__ void cursor_init(const int* __restrict__ offs, int* __restrict__ cur, int total) {
    int i = blockIdx.x * blockDim.x + threadIdx.x;
    if (i >= total) return;
    int r = i / NN;
    int n = i - r * NN;
    cur[i] = offs[(size_t)r * (NN + 1) + n];
}

__global__ void fill_kernel(const int* __restrict__ src, const int* __restrict__ dst,
                            int* __restrict__ cur, int* __restrict__ srcs,
                            int RE, int Eper) {
    int i = blockIdx.x * blockDim.x + threadIdx.x;
    if (i >= RE) return;
    int r = i / Eper;
    int d = dst[i];
    int pos = atomicAdd(&cur[r * NN + d], 1);
    srcs[(size_t)r * Eper + pos] = src[i];
}

// ---------------------------------------------------------------------------
// Weight prep: fp32 -> bf16, transposed to n-major [Ncols][K]
// ---------------------------------------------------------------------------
__global__ void convert_x(const float* __restrict__ x, unsigned short* __restrict__ xpad) {
    int row = blockIdx.x;          // < MPAD
    int col = threadIdx.x;         // < 320
    float v = (row < NN && col < FF) ? x[(size_t)row * FF + col] : 0.f;
    xpad[(size_t)row * 320 + col] = f2bf(v);
}

__global__ void wprep_feat(const float* __restrict__ W, unsigned short* __restrict__ Bt) {
    int n = blockIdx.x;            // < 256
    int k = threadIdx.x;           // < 320
    float v = (k < FF) ? W[(size_t)k * HH + n] : 0.f;
    Bt[(size_t)n * 320 + k] = f2bf(v);
}

// Bt[n][k], K=1024: k<256 -> skip_W[k][n]; else gcn_W[seg-1][k&255][n]/3
__global__ void wprep_layer(const float* __restrict__ skipW, const float* __restrict__ gcnW,
                            unsigned short* __restrict__ Bt) {
    int idx = blockIdx.x * blockDim.x + threadIdx.x;   // 256*1024
    int n = idx >> 10, k = idx & 1023;
    int seg = k >> 8, k2 = k & 255;
    float v = (seg == 0) ? skipW[(size_t)k2 * HH + n]
                         : gcnW[(size_t)(seg - 1) * HH * HH + (size_t)k2 * HH + n] * (1.0f / 3.0f);
    Bt[(size_t)n * 1024 + k] = f2bf(v);
}

__global__ void bias_layer(const float* __restrict__ skip_b, const float* __restrict__ gcn_b,
                           float* __restrict__ bias) {
    int t = threadIdx.x;  // 256
    bias[t] = skip_b[t] + (gcn_b[t] + gcn_b[HH + t] + gcn_b[2 * HH + t]) * (1.0f / 3.0f);
}

__global__ void wprep_c1(const float* __restrict__ W, unsigned short* __restrict__ Bt) {
    int idx = blockIdx.x * blockDim.x + threadIdx.x;   // 256*256
    int n = idx >> 8, k = idx & 255;
    Bt[(size_t)n * HH + k] = f2bf(W[(size_t)k * HH + n]);
}

__global__ void wprep_c2(const float* __restrict__ W, unsigned short* __restrict__ Bt) {
    int n = blockIdx.x;            // < 128
    int k = threadIdx.x;           // < 256
    float v = (n < CC) ? W[(size_t)k * CC + n] : 0.f;
    Bt[(size_t)n * HH + k] = f2bf(v);
}

// ---------------------------------------------------------------------------
// Aggregation (bf16): grid (NN/4, RR). One wave per dst node.
// Reads hcat cols 0..255, writes hcat cols 256*(r+1)..
// ---------------------------------------------------------------------------
__global__ __launch_bounds__(256) void agg_bf16(unsigned short* __restrict__ hcat,
                                                const int* __restrict__ offs_all,
                                                const int* __restrict__ srcs_all,
                                                const float* __restrict__ rs_out_all,
                                                const float* __restrict__ rs_in_all) {
    int r = blockIdx.y;
    const int* offs = offs_all + (size_t)r * (NN + 1);
    const int* srcs = srcs_all + (size_t)r * EE;
    const float* rs_o = rs_out_all + (size_t)r * NN;
    const float* rs_i = rs_in_all + (size_t)r * NN;
    int wave = threadIdx.x >> 6;
    int lane = threadIdx.x & 63;
    int node = blockIdx.x * 4 + wave;
    if (node >= NN) return;
    int s0 = offs[node], s1 = offs[node + 1];
    float a0 = 0.f, a1 = 0.f, a2 = 0.f, a3 = 0.f;
    for (int k = s0; k < s1; k++) {
        int s = srcs[k];
        float w = rs_o[s];
        ushort4 hv = *(const ushort4*)(hcat + (size_t)s * 1024 + lane * 4);
        a0 += w * bf2f(hv.x); a1 += w * bf2f(hv.y);
        a2 += w * bf2f(hv.z); a3 += w * bf2f(hv.w);
    }
    float wi = rs_i[node];
    ushort4 o;
    o.x = f2bf(a0 * wi); o.y = f2bf(a1 * wi);
    o.z = f2bf(a2 * wi); o.w = f2bf(a3 * wi);
    *(ushort4*)(hcat + (size_t)node * 1024 + 256 * (r + 1) + lane * 4) = o;
}

// ---------------------------------------------------------------------------
// bf16 MFMA GEMM: C[fp32] = A[bf16, ldA] @ Bt[bf16, n-major, ld=K] + bias
// 128x128 tile, BK=32, 4 waves, each wave 64x64 (4x4 of 16x16x32 MFMA).
// LDS staged via global_load_lds(16B) with XOR swizzle (conflict-free reads).
// ---------------------------------------------------------------------------
__global__ __launch_bounds__(256) void mfma_gemm(const unsigned short* __restrict__ A, int ldA,
                                                 const unsigned short* __restrict__ Bt,
                                                 const float* __restrict__ bias,
                                                 float* __restrict__ C, int ldC,
                                                 int Nstore, int K) {
    __shared__ unsigned short ldsA[128 * 32];
    __shared__ unsigned short ldsB[128 * 32];
    int tid = threadIdx.x;
    int w = tid >> 6, lane = tid & 63;
    int quad = lane >> 4, lr = lane & 15;
    int bm = blockIdx.y * 128, bn = blockIdx.x * 128;
    int wm = w >> 1, wn = w & 1;
    int lrow = lane >> 2;   // 0..15: row within a 16-row chunk
    int lslot = lane & 3;   // 16B slot

    f32x4 acc[4][4];
#pragma unroll
    for (int i = 0; i < 4; i++)
#pragma unroll
        for (int j = 0; j < 4; j++) acc[i][j] = (f32x4){0.f, 0.f, 0.f, 0.f};

    for (int k0 = 0; k0 < K; k0 += 32) {
#pragma unroll
        for (int c = 0; c < 2; c++) {
            int cc = w * 2 + c;            // chunk 0..7 (16 rows each)
            int rA = cc * 16 + lrow;       // local row / local n
            int cg = lslot ^ ((rA >> 1) & 3);
            gl_lds16(A + (size_t)(bm + rA) * ldA + k0 + cg * 8, &ldsA[cc * 512]);
            gl_lds16(Bt + (size_t)(bn + rA) * K + k0 + cg * 8, &ldsB[cc * 512]);
        }
        __syncthreads();
        bf16x8 af[4], bfr[4];
#pragma unroll
        for (int i = 0; i < 4; i++) {
            int r = wm * 64 + i * 16 + lr;
            int s = quad ^ ((r >> 1) & 3);
            af[i] = *(const bf16x8*)&ldsA[r * 32 + s * 8];
        }
#pragma unroll
        for (int j = 0; j < 4; j++) {
            int n = wn * 64 + j * 16 + lr;
            int s = quad ^ ((n >> 1) & 3);
            bfr[j] = *(const bf16x8*)&ldsB[n * 32 + s * 8];
        }
#pragma unroll
        for (int i = 0; i < 4; i++)
#pragma unroll
            for (int j = 0; j < 4; j++)
                acc[i][j] = __builtin_amdgcn_mfma_f32_16x16x32_bf16(af[i], bfr[j], acc[i][j], 0, 0, 0);
        __syncthreads();
    }

#pragma unroll
    for (int j = 0; j < 4; j++) {
        int col = bn + wn * 64 + j * 16 + lr;
        if (col >= Nstore) continue;
        float bv = bias ? bias[col] : 0.f;
#pragma unroll
        for (int i = 0; i < 4; i++) {
#pragma unroll
            for (int v = 0; v < 4; v++) {
                int row = bm + wm * 64 + i * 16 + quad * 4 + v;
                if (row < NN) C[(size_t)row * ldC + col] = acc[i][j][v] + bv;
            }
        }
    }
}

// ---------------------------------------------------------------------------
// BatchNorm
// ---------------------------------------------------------------------------
__global__ __launch_bounds__(256) void bn_stats(const float* __restrict__ Z,
                                                float* __restrict__ stats, int M) {
    int col = threadIdx.x;
    int r0 = blockIdx.x * 128;
    int rend = r0 + 128; if (rend > M) rend = M;
    float s = 0.f, s2 = 0.f;
    for (int r = r0; r < rend; r++) {
        float v = Z[(size_t)r * HH + col];
        s += v; s2 += v * v;
    }
    atomicAdd(&stats[col], s);
    atomicAdd(&stats[HH + col], s2);
}

// act: 1 = relu, 2 = leaky relu (0.01). Writes bf16 at out[row*ld_out+col].
__global__ __launch_bounds__(256) void bn_apply_bf16(const float* __restrict__ Z,
                                                     const float* __restrict__ stats,
                                                     const float* __restrict__ g,
                                                     const float* __restrict__ b,
                                                     unsigned short* __restrict__ out,
                                                     int ld_out, int act, float invM) {
    int idx = blockIdx.x * blockDim.x + threadIdx.x;
    if (idx >= NN * HH) return;
    int row = idx >> 8, col = idx & 255;
    float mean = stats[col] * invM;
    float var = stats[HH + col] * invM - mean * mean;
    float inv = rsqrtf(var + 1e-5f);
    float v = (Z[idx] - mean) * inv * g[col] + b[col];
    if (act == 1) v = fmaxf(v, 0.f);
    else if (act == 2) v = (v < 0.f) ? 0.01f * v : v;
    out[(size_t)row * ld_out + col] = f2bf(v);
}

// ---------------------------------------------------------------------------
extern "C" void kernel_launch(void* const* d_in, const int* in_sizes, int n_in,
                              void* d_out, int out_size, void* d_ws, size_t ws_size,
                              hipStream_t stream) {
    const float* x        = (const float*)d_in[0];
    const int*   esrc     = (const int*)d_in[1];
    const int*   edst     = (const int*)d_in[2];
    const float* W_feat   = (const float*)d_in[3];
    const float* b_feat   = (const float*)d_in[4];
    const float* g_feat   = (const float*)d_in[5];
    const float* beta_feat= (const float*)d_in[6];
    const float* gcn_W    = (const float*)d_in[7];
    const float* gcn_b    = (const float*)d_in[8];
    const float* skip_W   = (const float*)d_in[9];
    const float* skip_b   = (const float*)d_in[10];
    const float* bn_g     = (const float*)d_in[11];
    const float* bn_b     = (const float*)d_in[12];
    const float* W_c1     = (const float*)d_in[13];
    const float* b_c1     = (const float*)d_in[14];
    const float* g_c      = (const float*)d_in[15];
    const float* beta_c   = (const float*)d_in[16];
    const float* W_c2     = (const float*)d_in[17];
    const float* b_c2     = (const float*)d_in[18];
    float* out = (float*)d_out;
    (void)in_sizes; (void)n_in; (void)out_size; (void)ws_size;

    // Workspace layout (256B-aligned slices)
    char* w = (char*)d_ws;
    size_t off = 0;
    auto alloc = [&](size_t bytes) { void* p = w + off; off += (bytes + 255) & ~(size_t)255; return p; };
    unsigned short* hcat = (unsigned short*)alloc((size_t)MPAD * 1024 * 2);  // [MPAD][1024] bf16; xpad aliases base
    unsigned short* xpad = hcat;                                             // [MPAD][320] bf16 (dead after feat GEMM)
    float* f_acc   = (float*)alloc((size_t)NN * HH * 4);
    float* f_stats = (float*)alloc(2 * HH * 4);
    float* f_rs_out = (float*)alloc((size_t)RR * NN * 4);
    float* f_rs_in  = (float*)alloc((size_t)RR * NN * 4);
    int* i_cnt_out = (int*)alloc((size_t)RR * NN * 4);
    int* i_cnt_in  = (int*)alloc((size_t)RR * NN * 4);
    int* i_off     = (int*)alloc((size_t)RR * (NN + 1) * 4);
    int* i_cur     = (int*)alloc((size_t)RR * NN * 4);
    int* i_srcs    = (int*)alloc((size_t)RR * EE * 4);
    unsigned short* Bt_feat = (unsigned short*)alloc(256 * 320 * 2);
    unsigned short* Bt_l0   = (unsigned short*)alloc(256 * 1024 * 2);
    unsigned short* Bt_l1   = (unsigned short*)alloc(256 * 1024 * 2);
    unsigned short* Bt_c1   = (unsigned short*)alloc(256 * 256 * 2);
    unsigned short* Bt_c2   = (unsigned short*)alloc(128 * 256 * 2);
    float* bias_l0 = (float*)alloc(HH * 4);
    float* bias_l1 = (float*)alloc(HH * 4);

    const float invM = 1.0f / (float)NN;
    const int RE = RR * EE;

    // --- CSR + degrees ---
    hipMemsetAsync(i_cnt_out, 0, (size_t)RR * NN * 4, stream);
    hipMemsetAsync(i_cnt_in, 0, (size_t)RR * NN * 4, stream);
    hist_kernel<<<cdiv_h(RE, 256), 256, 0, stream>>>(esrc, edst, i_cnt_out, i_cnt_in, RE, EE);
    rs_kernel<<<cdiv_h(RR * NN, 256), 256, 0, stream>>>(i_cnt_out, i_cnt_in, f_rs_out, f_rs_in, RR * NN);
    scan_kernel<<<RR, 1024, 0, stream>>>(i_cnt_in, i_off);
    cursor_init<<<cdiv_h(RR * NN, 256), 256, 0, stream>>>(i_off, i_cur, RR * NN);
    fill_kernel<<<cdiv_h(RE, 256), 256, 0, stream>>>(esrc, edst, i_cur, i_srcs, RE, EE);

    // --- weight prep (bf16, transposed) ---
    convert_x<<<MPAD, 320, 0, stream>>>(x, xpad);
    wprep_feat<<<256, 320, 0, stream>>>(W_feat, Bt_feat);
    wprep_layer<<<1024, 256, 0, stream>>>(skip_W, gcn_W, Bt_l0);
    wprep_layer<<<1024, 256, 0, stream>>>(skip_W + (size_t)HH * HH, gcn_W + (size_t)RR * HH * HH, Bt_l1);
    bias_layer<<<1, 256, 0, stream>>>(skip_b, gcn_b, bias_l0);
    bias_layer<<<1, 256, 0, stream>>>(skip_b + HH, gcn_b + (size_t)RR * HH, bias_l1);
    wprep_c1<<<256, 256, 0, stream>>>(W_c1, Bt_c1);
    wprep_c2<<<128, 256, 0, stream>>>(W_c2, Bt_c2);

    dim3 grid_H(2, MPAD / 128);
    dim3 grid_C(1, MPAD / 128);
    const int nblk_e = cdiv_h(NN * HH, 256);

    // --- feat_reduce: h = relu(BN(x @ W_feat + b_feat)) -> hcat[:,0:256] bf16 ---
    mfma_gemm<<<grid_H, 256, 0, stream>>>(xpad, 320, Bt_feat, b_feat, f_acc, HH, HH, 320);
    hipMemsetAsync(f_stats, 0, 2 * HH * 4, stream);
    bn_stats<<<cdiv_h(NN, 128), 256, 0, stream>>>(f_acc, f_stats, NN);
    bn_apply_bf16<<<nblk_e, 256, 0, stream>>>(f_acc, f_stats, g_feat, beta_feat, hcat, 1024, 1, invM);

    // --- GCN layers: one K=1024 GEMM per layer ---
    for (int l = 0; l < LL; l++) {
        agg_bf16<<<dim3(cdiv_h(NN, 4), RR), 256, 0, stream>>>(hcat, i_off, i_srcs, f_rs_out, f_rs_in);
        mfma_gemm<<<grid_H, 256, 0, stream>>>(hcat, 1024, l ? Bt_l1 : Bt_l0,
                                              l ? bias_l1 : bias_l0, f_acc, HH, HH, 1024);
        hipMemsetAsync(f_stats, 0, 2 * HH * 4, stream);
        bn_stats<<<cdiv_h(NN, 128), 256, 0, stream>>>(f_acc, f_stats, NN);
        bn_apply_bf16<<<nblk_e, 256, 0, stream>>>(f_acc, f_stats, bn_g + (size_t)l * HH,
                                                  bn_b + (size_t)l * HH, hcat, 1024, 2, invM);
    }

    // --- head ---
    mfma_gemm<<<grid_H, 256, 0, stream>>>(hcat, 1024, Bt_c1, b_c1, f_acc, HH, HH, 256);
    hipMemsetAsync(f_stats, 0, 2 * HH * 4, stream);
    bn_stats<<<cdiv_h(NN, 128), 256, 0, stream>>>(f_acc, f_stats, NN);
    bn_apply_bf16<<<nblk_e, 256, 0, stream>>>(f_acc, f_stats, g_c, beta_c, hcat + 256, 1024, 1, invM);
    mfma_gemm<<<grid_C, 256, 0, stream>>>(hcat + 256, 1024, Bt_c2, b_c2, out, CC, CC, 256);
}

// Round 4
// 1567.104 us; speedup vs baseline: 2.5141x; 1.1849x over previous
//
#include <hip/hip_runtime.h>

#define NN 100000   // nodes
#define EE 500000   // edges per relation
#define RR 3        // relations
#define LL 2        // layers
#define FF 300      // input features
#define HH 256      // hidden
#define CC 23       // classes
#define MPAD 100096 // 782 * 128

static inline int cdiv_h(int a, int b) { return (a + b - 1) / b; }

typedef __attribute__((ext_vector_type(8))) short bf16x8;
typedef __attribute__((ext_vector_type(4))) float f32x4;

__device__ inline unsigned short f2bf(float f) {
    union { float f; unsigned int u; } v; v.f = f;
    unsigned int r = v.u + 0x7fff + ((v.u >> 16) & 1);
    return (unsigned short)(r >> 16);
}
__device__ inline float bf2f(unsigned short u) {
    union { unsigned int u; float f; } v; v.u = ((unsigned int)u) << 16;
    return v.f;
}
__device__ inline void gl_lds16(const void* g, void* l) {
    __builtin_amdgcn_global_load_lds((const __attribute__((address_space(1))) unsigned int*)g,
                                     (__attribute__((address_space(3))) unsigned int*)l,
                                     16, 0, 0);
}

// ---------------------------------------------------------------------------
// CSR build
// ---------------------------------------------------------------------------
__global__ void hist_kernel(const int* __restrict__ src, const int* __restrict__ dst,
                            int* __restrict__ cnt_out, int* __restrict__ cnt_in,
                            int RE, int Eper) {
    int i = blockIdx.x * blockDim.x + threadIdx.x;
    if (i >= RE) return;
    int r = i / Eper;
    atomicAdd(&cnt_out[r * NN + src[i]], 1);
    atomicAdd(&cnt_in[r * NN + dst[i]], 1);
}

__global__ void rs_kernel(const int* __restrict__ cnt_out, const int* __restrict__ cnt_in,
                          float* __restrict__ rs_out, float* __restrict__ rs_in, int total) {
    int i = blockIdx.x * blockDim.x + threadIdx.x;
    if (i >= total) return;
    rs_out[i] = rsqrtf(fmaxf((float)cnt_out[i], 1.0f));
    rs_in[i]  = rsqrtf(fmaxf((float)cnt_in[i], 1.0f));
}

__global__ __launch_bounds__(1024) void scan_kernel(const int* __restrict__ cnt_in,
                                                    int* __restrict__ offs) {
    int r = blockIdx.x;
    const int* cnt = cnt_in + r * NN;
    int* off = offs + (size_t)r * (NN + 1);
    int t = threadIdx.x;
    const int chunk = (NN + 1023) / 1024;
    int lo = t * chunk;
    int hi = lo + chunk; if (hi > NN) hi = NN; if (lo > NN) lo = NN;
    int s = 0;
    for (int i = lo; i < hi; i++) s += cnt[i];
    __shared__ int sh[1024];
    sh[t] = s;
    __syncthreads();
    for (int d = 1; d < 1024; d <<= 1) {
        int v = (t >= d) ? sh[t - d] : 0;
        __syncthreads();
        sh[t] += v;
        __syncthreads();
    }
    int run = sh[t] - s;
    for (int i = lo; i < hi; i++) { off[i] = run; run += cnt[i]; }
    if (t == 1023) off[NN] = sh[1023];
}

__global__ void cursor_init(const int* __restrict__ offs, int* __restrict__ cur, int total) {
    int i = blockIdx.x * blockDim.x + threadIdx.x;
    if (i >= total) return;
    int r = i / NN;
    int n = i - r * NN;
    cur[i] = offs[(size_t)r * (NN + 1) + n];
}

__global__ void fill_kernel(const int* __restrict__ src, const int* __restrict__ dst,
                            int* __restrict__ cur, int* __restrict__ srcs,
                            int RE, int Eper) {
    int i = blockIdx.x * blockDim.x + threadIdx.x;
    if (i >= RE) return;
    int r = i / Eper;
    int d = dst[i];
    int pos = atomicAdd(&cur[r * NN + d], 1);
    srcs[(size_t)r * Eper + pos] = src[i];
}

// ---------------------------------------------------------------------------
// Weight prep: fp32 -> bf16, transposed to n-major [Ncols][K]
// ---------------------------------------------------------------------------
__global__ void convert_x(const float* __restrict__ x, unsigned short* __restrict__ xpad) {
    int row = blockIdx.x;
    int col = threadIdx.x;
    float v = (row < NN && col < FF) ? x[(size_t)row * FF + col] : 0.f;
    xpad[(size_t)row * 320 + col] = f2bf(v);
}

__global__ void wprep_feat(const float* __restrict__ W, unsigned short* __restrict__ Bt) {
    int n = blockIdx.x;
    int k = threadIdx.x;
    float v = (k < FF) ? W[(size_t)k * HH + n] : 0.f;
    Bt[(size_t)n * 320 + k] = f2bf(v);
}

__global__ void wprep_layer(const float* __restrict__ skipW, const float* __restrict__ gcnW,
                            unsigned short* __restrict__ Bt) {
    int idx = blockIdx.x * blockDim.x + threadIdx.x;
    int n = idx >> 10, k = idx & 1023;
    int seg = k >> 8, k2 = k & 255;
    float v = (seg == 0) ? skipW[(size_t)k2 * HH + n]
                         : gcnW[(size_t)(seg - 1) * HH * HH + (size_t)k2 * HH + n] * (1.0f / 3.0f);
    Bt[(size_t)n * 1024 + k] = f2bf(v);
}

__global__ void bias_layer(const float* __restrict__ skip_b, const float* __restrict__ gcn_b,
                           float* __restrict__ bias) {
    int t = threadIdx.x;
    bias[t] = skip_b[t] + (gcn_b[t] + gcn_b[HH + t] + gcn_b[2 * HH + t]) * (1.0f / 3.0f);
}

__global__ void wprep_c1(const float* __restrict__ W, unsigned short* __restrict__ Bt) {
    int idx = blockIdx.x * blockDim.x + threadIdx.x;
    int n = idx >> 8, k = idx & 255;
    Bt[(size_t)n * HH + k] = f2bf(W[(size_t)k * HH + n]);
}

__global__ void wprep_c2(const float* __restrict__ W, unsigned short* __restrict__ Bt) {
    int n = blockIdx.x;
    int k = threadIdx.x;
    float v = (n < CC) ? W[(size_t)k * CC + n] : 0.f;
    Bt[(size_t)n * HH + k] = f2bf(v);
}

// ---------------------------------------------------------------------------
// Aggregation (bf16): grid (NN/4, RR). One wave per dst node.
// MLP version: preload edge indices lane-parallel, shfl-broadcast, issue 4
// independent 512B row loads per iteration.
// ---------------------------------------------------------------------------
__global__ __launch_bounds__(256) void agg_bf16(unsigned short* __restrict__ hcat,
                                                const int* __restrict__ offs_all,
                                                const int* __restrict__ srcs_all,
                                                const float* __restrict__ rs_out_all,
                                                const float* __restrict__ rs_in_all) {
    int r = blockIdx.y;
    const int* offs = offs_all + (size_t)r * (NN + 1);
    const int* srcs = srcs_all + (size_t)r * EE;
    const float* rs_o = rs_out_all + (size_t)r * NN;
    const float* rs_i = rs_in_all + (size_t)r * NN;
    int wave = threadIdx.x >> 6;
    int lane = threadIdx.x & 63;
    int node = blockIdx.x * 4 + wave;
    if (node >= NN) return;
    int s0 = offs[node], s1 = offs[node + 1];
    const unsigned short* hb = hcat + lane * 4;
    float a0 = 0.f, a1 = 0.f, a2 = 0.f, a3 = 0.f;
    for (int c0 = s0; c0 < s1; c0 += 64) {
        int cnt = s1 - c0; if (cnt > 64) cnt = 64;
        int sk = 0; float wk = 0.f;
        if (lane < cnt) { sk = srcs[c0 + lane]; wk = rs_o[sk]; }
        int j = 0;
        for (; j + 4 <= cnt; j += 4) {
            int t0 = __shfl(sk, j), t1 = __shfl(sk, j + 1);
            int t2 = __shfl(sk, j + 2), t3 = __shfl(sk, j + 3);
            float u0 = __shfl(wk, j), u1 = __shfl(wk, j + 1);
            float u2 = __shfl(wk, j + 2), u3 = __shfl(wk, j + 3);
            ushort4 h0 = *(const ushort4*)(hb + (size_t)t0 * 1024);
            ushort4 h1 = *(const ushort4*)(hb + (size_t)t1 * 1024);
            ushort4 h2 = *(const ushort4*)(hb + (size_t)t2 * 1024);
            ushort4 h3 = *(const ushort4*)(hb + (size_t)t3 * 1024);
            a0 += u0 * bf2f(h0.x) + u1 * bf2f(h1.x) + u2 * bf2f(h2.x) + u3 * bf2f(h3.x);
            a1 += u0 * bf2f(h0.y) + u1 * bf2f(h1.y) + u2 * bf2f(h2.y) + u3 * bf2f(h3.y);
            a2 += u0 * bf2f(h0.z) + u1 * bf2f(h1.z) + u2 * bf2f(h2.z) + u3 * bf2f(h3.z);
            a3 += u0 * bf2f(h0.w) + u1 * bf2f(h1.w) + u2 * bf2f(h2.w) + u3 * bf2f(h3.w);
        }
        int rem = cnt - j;
        if (rem > 0) {
            int t0 = __shfl(sk, j);
            int t1 = __shfl(sk, rem > 1 ? j + 1 : j);
            int t2 = __shfl(sk, rem > 2 ? j + 2 : j);
            float u0 = __shfl(wk, j);
            float u1 = rem > 1 ? __shfl(wk, j + 1) : 0.f;
            float u2 = rem > 2 ? __shfl(wk, j + 2) : 0.f;
            ushort4 h0 = *(const ushort4*)(hb + (size_t)t0 * 1024);
            ushort4 h1 = *(const ushort4*)(hb + (size_t)t1 * 1024);
            ushort4 h2 = *(const ushort4*)(hb + (size_t)t2 * 1024);
            a0 += u0 * bf2f(h0.x) + u1 * bf2f(h1.x) + u2 * bf2f(h2.x);
            a1 += u0 * bf2f(h0.y) + u1 * bf2f(h1.y) + u2 * bf2f(h2.y);
            a2 += u0 * bf2f(h0.z) + u1 * bf2f(h1.z) + u2 * bf2f(h2.z);
            a3 += u0 * bf2f(h0.w) + u1 * bf2f(h1.w) + u2 * bf2f(h2.w);
        }
    }
    float wi = rs_i[node];
    ushort4 o;
    o.x = f2bf(a0 * wi); o.y = f2bf(a1 * wi);
    o.z = f2bf(a2 * wi); o.w = f2bf(a3 * wi);
    *(ushort4*)(hcat + (size_t)node * 1024 + 256 * (r + 1) + lane * 4) = o;
}

// ---------------------------------------------------------------------------
// bf16 MFMA GEMM + optional fused BN column stats (sum, sumsq) in epilogue.
// C[fp32] = A[bf16, ldA] @ Bt[bf16, n-major, ld=K] + bias
// ---------------------------------------------------------------------------
__global__ __launch_bounds__(256) void mfma_gemm(const unsigned short* __restrict__ A, int ldA,
                                                 const unsigned short* __restrict__ Bt,
                                                 const float* __restrict__ bias,
                                                 float* __restrict__ C, int ldC,
                                                 int Nstore, int K,
                                                 float* __restrict__ stats) {
    __shared__ unsigned short ldsA[128 * 32];
    __shared__ unsigned short ldsB[128 * 32];
    int tid = threadIdx.x;
    int w = tid >> 6, lane = tid & 63;
    int quad = lane >> 4, lr = lane & 15;
    int bm = blockIdx.y * 128, bn = blockIdx.x * 128;
    int wm = w >> 1, wn = w & 1;
    int lrow = lane >> 2;
    int lslot = lane & 3;

    f32x4 acc[4][4];
#pragma unroll
    for (int i = 0; i < 4; i++)
#pragma unroll
        for (int j = 0; j < 4; j++) acc[i][j] = (f32x4){0.f, 0.f, 0.f, 0.f};

    for (int k0 = 0; k0 < K; k0 += 32) {
#pragma unroll
        for (int c = 0; c < 2; c++) {
            int cc = w * 2 + c;
            int rA = cc * 16 + lrow;
            int cg = lslot ^ ((rA >> 1) & 3);
            gl_lds16(A + (size_t)(bm + rA) * ldA + k0 + cg * 8, &ldsA[cc * 512]);
            gl_lds16(Bt + (size_t)(bn + rA) * K + k0 + cg * 8, &ldsB[cc * 512]);
        }
        __syncthreads();
        bf16x8 af[4], bfr[4];
#pragma unroll
        for (int i = 0; i < 4; i++) {
            int r = wm * 64 + i * 16 + lr;
            int s = quad ^ ((r >> 1) & 3);
            af[i] = *(const bf16x8*)&ldsA[r * 32 + s * 8];
        }
#pragma unroll
        for (int j = 0; j < 4; j++) {
            int n = wn * 64 + j * 16 + lr;
            int s = quad ^ ((n >> 1) & 3);
            bfr[j] = *(const bf16x8*)&ldsB[n * 32 + s * 8];
        }
#pragma unroll
        for (int i = 0; i < 4; i++)
#pragma unroll
            for (int j = 0; j < 4; j++)
                acc[i][j] = __builtin_amdgcn_mfma_f32_16x16x32_bf16(af[i], bfr[j], acc[i][j], 0, 0, 0);
        __syncthreads();
    }

#pragma unroll
    for (int j = 0; j < 4; j++) {
        int col = bn + wn * 64 + j * 16 + lr;
        if (col >= Nstore) continue;
        float bv = bias ? bias[col] : 0.f;
        float ssum = 0.f, ssq = 0.f;
#pragma unroll
        for (int i = 0; i < 4; i++) {
#pragma unroll
            for (int v = 0; v < 4; v++) {
                int row = bm + wm * 64 + i * 16 + quad * 4 + v;
                if (row < NN) {
                    float val = acc[i][j][v] + bv;
                    C[(size_t)row * ldC + col] = val;
                    ssum += val; ssq += val * val;
                }
            }
        }
        if (stats) {
            ssum += __shfl_xor(ssum, 16); ssum += __shfl_xor(ssum, 32);
            ssq  += __shfl_xor(ssq, 16);  ssq  += __shfl_xor(ssq, 32);
            if (quad == 0) {
                atomicAdd(&stats[col], ssum);
                atomicAdd(&stats[HH + col], ssq);
            }
        }
    }
}

// act: 1 = relu, 2 = leaky relu (0.01). Writes bf16 at out[row*ld_out+col].
__global__ __launch_bounds__(256) void bn_apply_bf16(const float* __restrict__ Z,
                                                     const float* __restrict__ stats,
                                                     const float* __restrict__ g,
                                                     const float* __restrict__ b,
                                                     unsigned short* __restrict__ out,
                                                     int ld_out, int act, float invM) {
    int idx = blockIdx.x * blockDim.x + threadIdx.x;
    if (idx >= NN * HH) return;
    int row = idx >> 8, col = idx & 255;
    float mean = stats[col] * invM;
    float var = stats[HH + col] * invM - mean * mean;
    float inv = rsqrtf(var + 1e-5f);
    float v = (Z[idx] - mean) * inv * g[col] + b[col];
    if (act == 1) v = fmaxf(v, 0.f);
    else if (act == 2) v = (v < 0.f) ? 0.01f * v : v;
    out[(size_t)row * ld_out + col] = f2bf(v);
}

// ---------------------------------------------------------------------------
extern "C" void kernel_launch(void* const* d_in, const int* in_sizes, int n_in,
                              void* d_out, int out_size, void* d_ws, size_t ws_size,
                              hipStream_t stream) {
    const float* x        = (const float*)d_in[0];
    const int*   esrc     = (const int*)d_in[1];
    const int*   edst     = (const int*)d_in[2];
    const float* W_feat   = (const float*)d_in[3];
    const float* b_feat   = (const float*)d_in[4];
    const float* g_feat   = (const float*)d_in[5];
    const float* beta_feat= (const float*)d_in[6];
    const float* gcn_W    = (const float*)d_in[7];
    const float* gcn_b    = (const float*)d_in[8];
    const float* skip_W   = (const float*)d_in[9];
    const float* skip_b   = (const float*)d_in[10];
    const float* bn_g     = (const float*)d_in[11];
    const float* bn_b     = (const float*)d_in[12];
    const float* W_c1     = (const float*)d_in[13];
    const float* b_c1     = (const float*)d_in[14];
    const float* g_c      = (const float*)d_in[15];
    const float* beta_c   = (const float*)d_in[16];
    const float* W_c2     = (const float*)d_in[17];
    const float* b_c2     = (const float*)d_in[18];
    float* out = (float*)d_out;
    (void)in_sizes; (void)n_in; (void)out_size; (void)ws_size;

    char* w = (char*)d_ws;
    size_t off = 0;
    auto alloc = [&](size_t bytes) { void* p = w + off; off += (bytes + 255) & ~(size_t)255; return p; };
    unsigned short* hcat = (unsigned short*)alloc((size_t)MPAD * 1024 * 2);
    unsigned short* xpad = hcat;  // [MPAD][320] bf16, dead after feat GEMM
    float* f_acc   = (float*)alloc((size_t)NN * HH * 4);
    float* f_stats = (float*)alloc(4 * 2 * HH * 4);   // 4 slices of [2][HH]
    float* f_rs_out = (float*)alloc((size_t)RR * NN * 4);
    float* f_rs_in  = (float*)alloc((size_t)RR * NN * 4);
    int* i_cnt_out = (int*)alloc((size_t)RR * NN * 4);
    int* i_cnt_in  = (int*)alloc((size_t)RR * NN * 4);
    int* i_off     = (int*)alloc((size_t)RR * (NN + 1) * 4);
    int* i_cur     = (int*)alloc((size_t)RR * NN * 4);
    int* i_srcs    = (int*)alloc((size_t)RR * EE * 4);
    unsigned short* Bt_feat = (unsigned short*)alloc(256 * 320 * 2);
    unsigned short* Bt_l0   = (unsigned short*)alloc(256 * 1024 * 2);
    unsigned short* Bt_l1   = (unsigned short*)alloc(256 * 1024 * 2);
    unsigned short* Bt_c1   = (unsigned short*)alloc(256 * 256 * 2);
    unsigned short* Bt_c2   = (unsigned short*)alloc(128 * 256 * 2);
    float* bias_l0 = (float*)alloc(HH * 4);
    float* bias_l1 = (float*)alloc(HH * 4);

    const float invM = 1.0f / (float)NN;
    const int RE = RR * EE;

    // --- CSR + degrees ---
    (void)hipMemsetAsync(i_cnt_out, 0, (size_t)RR * NN * 4, stream);
    (void)hipMemsetAsync(i_cnt_in, 0, (size_t)RR * NN * 4, stream);
    (void)hipMemsetAsync(f_stats, 0, 4 * 2 * HH * 4, stream);
    hist_kernel<<<cdiv_h(RE, 256), 256, 0, stream>>>(esrc, edst, i_cnt_out, i_cnt_in, RE, EE);
    rs_kernel<<<cdiv_h(RR * NN, 256), 256, 0, stream>>>(i_cnt_out, i_cnt_in, f_rs_out, f_rs_in, RR * NN);
    scan_kernel<<<RR, 1024, 0, stream>>>(i_cnt_in, i_off);
    cursor_init<<<cdiv_h(RR * NN, 256), 256, 0, stream>>>(i_off, i_cur, RR * NN);
    fill_kernel<<<cdiv_h(RE, 256), 256, 0, stream>>>(esrc, edst, i_cur, i_srcs, RE, EE);

    // --- weight prep (bf16, transposed) ---
    convert_x<<<MPAD, 320, 0, stream>>>(x, xpad);
    wprep_feat<<<256, 320, 0, stream>>>(W_feat, Bt_feat);
    wprep_layer<<<1024, 256, 0, stream>>>(skip_W, gcn_W, Bt_l0);
    wprep_layer<<<1024, 256, 0, stream>>>(skip_W + (size_t)HH * HH, gcn_W + (size_t)RR * HH * HH, Bt_l1);
    bias_layer<<<1, 256, 0, stream>>>(skip_b, gcn_b, bias_l0);
    bias_layer<<<1, 256, 0, stream>>>(skip_b + HH, gcn_b + (size_t)RR * HH, bias_l1);
    wprep_c1<<<256, 256, 0, stream>>>(W_c1, Bt_c1);
    wprep_c2<<<128, 256, 0, stream>>>(W_c2, Bt_c2);

    dim3 grid_H(2, MPAD / 128);
    dim3 grid_C(1, MPAD / 128);
    const int nblk_e = cdiv_h(NN * HH, 256);
    float* st0 = f_stats;
    float* st1 = f_stats + 2 * HH;
    float* st2 = f_stats + 4 * HH;
    float* st3 = f_stats + 6 * HH;

    // --- feat_reduce: h = relu(BN(x @ W_feat + b_feat)) -> hcat[:,0:256] bf16 ---
    mfma_gemm<<<grid_H, 256, 0, stream>>>(xpad, 320, Bt_feat, b_feat, f_acc, HH, HH, 320, st0);
    bn_apply_bf16<<<nblk_e, 256, 0, stream>>>(f_acc, st0, g_feat, beta_feat, hcat, 1024, 1, invM);

    // --- GCN layers: one K=1024 GEMM per layer ---
    for (int l = 0; l < LL; l++) {
        agg_bf16<<<dim3(cdiv_h(NN, 4), RR), 256, 0, stream>>>(hcat, i_off, i_srcs, f_rs_out, f_rs_in);
        float* st = l ? st2 : st1;
        mfma_gemm<<<grid_H, 256, 0, stream>>>(hcat, 1024, l ? Bt_l1 : Bt_l0,
                                              l ? bias_l1 : bias_l0, f_acc, HH, HH, 1024, st);
        bn_apply_bf16<<<nblk_e, 256, 0, stream>>>(f_acc, st, bn_g + (size_t)l * HH,
                                                  bn_b + (size_t)l * HH, hcat, 1024, 2, invM);
    }

    // --- head ---
    mfma_gemm<<<grid_H, 256, 0, stream>>>(hcat, 1024, Bt_c1, b_c1, f_acc, HH, HH, 256, st3);
    bn_apply_bf16<<<nblk_e, 256, 0, stream>>>(f_acc, st3, g_c, beta_c, hcat + 256, 1024, 1, invM);
    mfma_gemm<<<grid_C, 256, 0, stream>>>(hcat + 256, 1024, Bt_c2, b_c2, out, CC, CC, 256, nullptr);
}

// Round 5
// 1263.829 us; speedup vs baseline: 3.1174x; 1.2400x over previous
//
#include <hip/hip_runtime.h>

#define NN 100000   // nodes
#define EE 500000   // edges per relation
#define RR 3        // relations
#define LL 2        // layers
#define FF 300      // input features
#define HH 256      // hidden
#define CC 23       // classes
#define MPAD 100096 // 782 * 128
#define SCHUNK 2048
#define SNB ((NN + SCHUNK - 1) / SCHUNK)   // 49

static inline int cdiv_h(int a, int b) { return (a + b - 1) / b; }

typedef __attribute__((ext_vector_type(8))) short bf16x8;
typedef __attribute__((ext_vector_type(4))) float f32x4;

__device__ inline unsigned short f2bf(float f) {
    union { float f; unsigned int u; } v; v.f = f;
    unsigned int r = v.u + 0x7fff + ((v.u >> 16) & 1);
    return (unsigned short)(r >> 16);
}
__device__ inline float bf2f(unsigned short u) {
    union { unsigned int u; float f; } v; v.u = ((unsigned int)u) << 16;
    return v.f;
}
__device__ inline void gl_lds16(const void* g, void* l) {
    __builtin_amdgcn_global_load_lds((const __attribute__((address_space(1))) unsigned int*)g,
                                     (__attribute__((address_space(3))) unsigned int*)l,
                                     16, 0, 0);
}

// ---------------------------------------------------------------------------
// CSR build
// ---------------------------------------------------------------------------
__global__ void hist_kernel(const int* __restrict__ src, const int* __restrict__ dst,
                            int* __restrict__ cnt_out, int* __restrict__ cnt_in,
                            int RE, int Eper) {
    int i = blockIdx.x * blockDim.x + threadIdx.x;
    if (i >= RE) return;
    int r = i / Eper;
    atomicAdd(&cnt_out[r * NN + src[i]], 1);
    atomicAdd(&cnt_in[r * NN + dst[i]], 1);
}

__global__ void rs_kernel(const int* __restrict__ cnt_out, const int* __restrict__ cnt_in,
                          float* __restrict__ rs_out, float* __restrict__ rs_in, int total) {
    int i = blockIdx.x * blockDim.x + threadIdx.x;
    if (i >= total) return;
    rs_out[i] = rsqrtf(fmaxf((float)cnt_out[i], 1.0f));
    rs_in[i]  = rsqrtf(fmaxf((float)cnt_in[i], 1.0f));
}

// --- 3-phase exclusive scan of in-degree counts -> CSR offsets + cursors ---
__global__ __launch_bounds__(256) void scan_a(const int* __restrict__ cnt, int* __restrict__ bsum) {
    int r = blockIdx.y, b = blockIdx.x, t = threadIdx.x;
    const int* c = cnt + (size_t)r * NN;
    int base = b * SCHUNK;
    int s = 0;
    for (int i = t; i < SCHUNK; i += 256) {
        int idx = base + i;
        if (idx < NN) s += c[idx];
    }
#pragma unroll
    for (int o = 1; o < 64; o <<= 1) s += __shfl_xor(s, o);
    __shared__ int sh[4];
    if ((t & 63) == 0) sh[t >> 6] = s;
    __syncthreads();
    if (t == 0) bsum[r * SNB + b] = sh[0] + sh[1] + sh[2] + sh[3];
}

__global__ void scan_b(int* __restrict__ bsum, int* __restrict__ offs) {
    int r = threadIdx.x;
    if (r >= RR) return;
    int* bs = bsum + r * SNB;
    int run = 0;
    for (int i = 0; i < SNB; i++) { int v = bs[i]; bs[i] = run; run += v; }
    offs[(size_t)r * (NN + 1) + NN] = run;
}

__global__ __launch_bounds__(256) void scan_c(const int* __restrict__ cnt, const int* __restrict__ bsum,
                                              int* __restrict__ offs, int* __restrict__ cur) {
    int r = blockIdx.y, b = blockIdx.x, t = threadIdx.x;
    const int* c = cnt + (size_t)r * NN;
    int base = b * SCHUNK + t * 8;
    int v[8]; int s = 0;
#pragma unroll
    for (int j = 0; j < 8; j++) {
        int idx = base + j;
        v[j] = (idx < NN) ? c[idx] : 0;
        s += v[j];
    }
    __shared__ int sh[256];
    sh[t] = s;
    __syncthreads();
    for (int d = 1; d < 256; d <<= 1) {
        int x = (t >= d) ? sh[t - d] : 0;
        __syncthreads();
        sh[t] += x;
        __syncthreads();
    }
    int run = sh[t] - s + bsum[r * SNB + b];
    int* orow = offs + (size_t)r * (NN + 1);
    int* crow = cur + (size_t)r * NN;
#pragma unroll
    for (int j = 0; j < 8; j++) {
        int idx = base + j;
        if (idx < NN) { orow[idx] = run; crow[idx] = run; }
        run += v[j];
    }
}

__global__ void fill_kernel(const int* __restrict__ src, const int* __restrict__ dst,
                            int* __restrict__ cur, int* __restrict__ srcs,
                            int RE, int Eper) {
    int i = blockIdx.x * blockDim.x + threadIdx.x;
    if (i >= RE) return;
    int r = i / Eper;
    int d = dst[i];
    int pos = atomicAdd(&cur[r * NN + d], 1);
    srcs[(size_t)r * Eper + pos] = src[i];
}

// ---------------------------------------------------------------------------
// Weight prep: fp32 -> bf16, transposed to n-major [Ncols][K]
// ---------------------------------------------------------------------------
__global__ void convert_x(const float* __restrict__ x, unsigned short* __restrict__ xpad) {
    int row = blockIdx.x;
    int col = threadIdx.x;
    float v = (row < NN && col < FF) ? x[(size_t)row * FF + col] : 0.f;
    xpad[(size_t)row * 320 + col] = f2bf(v);
}

__global__ void wprep_feat(const float* __restrict__ W, unsigned short* __restrict__ Bt) {
    int n = blockIdx.x;
    int k = threadIdx.x;
    float v = (k < FF) ? W[(size_t)k * HH + n] : 0.f;
    Bt[(size_t)n * 320 + k] = f2bf(v);
}

__global__ void wprep_layer(const float* __restrict__ skipW, const float* __restrict__ gcnW,
                            unsigned short* __restrict__ Bt) {
    int idx = blockIdx.x * blockDim.x + threadIdx.x;
    int n = idx >> 10, k = idx & 1023;
    int seg = k >> 8, k2 = k & 255;
    float v = (seg == 0) ? skipW[(size_t)k2 * HH + n]
                         : gcnW[(size_t)(seg - 1) * HH * HH + (size_t)k2 * HH + n] * (1.0f / 3.0f);
    Bt[(size_t)n * 1024 + k] = f2bf(v);
}

__global__ void bias_layer(const float* __restrict__ skip_b, const float* __restrict__ gcn_b,
                           float* __restrict__ bias) {
    int t = threadIdx.x;
    bias[t] = skip_b[t] + (gcn_b[t] + gcn_b[HH + t] + gcn_b[2 * HH + t]) * (1.0f / 3.0f);
}

__global__ void wprep_c1(const float* __restrict__ W, unsigned short* __restrict__ Bt) {
    int idx = blockIdx.x * blockDim.x + threadIdx.x;
    int n = idx >> 8, k = idx & 255;
    Bt[(size_t)n * HH + k] = f2bf(W[(size_t)k * HH + n]);
}

__global__ void wprep_c2(const float* __restrict__ W, unsigned short* __restrict__ Bt) {
    int n = blockIdx.x;
    int k = threadIdx.x;
    float v = (n < CC) ? W[(size_t)k * CC + n] : 0.f;
    Bt[(size_t)n * HH + k] = f2bf(v);
}

// ---------------------------------------------------------------------------
// Aggregation (bf16): grid (NN/4, RR). One wave per dst node, unroll 8.
// ---------------------------------------------------------------------------
__global__ __launch_bounds__(256) void agg_bf16(unsigned short* __restrict__ hcat,
                                                const int* __restrict__ offs_all,
                                                const int* __restrict__ srcs_all,
                                                const float* __restrict__ rs_out_all,
                                                const float* __restrict__ rs_in_all) {
    int r = blockIdx.y;
    const int* offs = offs_all + (size_t)r * (NN + 1);
    const int* srcs = srcs_all + (size_t)r * EE;
    const float* rs_o = rs_out_all + (size_t)r * NN;
    const float* rs_i = rs_in_all + (size_t)r * NN;
    int wave = threadIdx.x >> 6;
    int lane = threadIdx.x & 63;
    int node = blockIdx.x * 4 + wave;
    if (node >= NN) return;
    int s0 = offs[node], s1 = offs[node + 1];
    const unsigned short* hb = hcat + lane * 4;
    float a0 = 0.f, a1 = 0.f, a2 = 0.f, a3 = 0.f;
    for (int c0 = s0; c0 < s1; c0 += 64) {
        int cnt = s1 - c0; if (cnt > 64) cnt = 64;
        int sk = 0; float wk = 0.f;
        if (lane < cnt) { sk = srcs[c0 + lane]; wk = rs_o[sk]; }
        int j = 0;
        for (; j + 8 <= cnt; j += 8) {
            int t_[8]; float u_[8]; ushort4 h_[8];
#pragma unroll
            for (int q = 0; q < 8; q++) { t_[q] = __shfl(sk, j + q); u_[q] = __shfl(wk, j + q); }
#pragma unroll
            for (int q = 0; q < 8; q++) h_[q] = *(const ushort4*)(hb + (size_t)t_[q] * 1024);
#pragma unroll
            for (int q = 0; q < 8; q++) {
                a0 += u_[q] * bf2f(h_[q].x); a1 += u_[q] * bf2f(h_[q].y);
                a2 += u_[q] * bf2f(h_[q].z); a3 += u_[q] * bf2f(h_[q].w);
            }
        }
        if (j + 4 <= cnt) {
            int t_[4]; float u_[4]; ushort4 h_[4];
#pragma unroll
            for (int q = 0; q < 4; q++) { t_[q] = __shfl(sk, j + q); u_[q] = __shfl(wk, j + q); }
#pragma unroll
            for (int q = 0; q < 4; q++) h_[q] = *(const ushort4*)(hb + (size_t)t_[q] * 1024);
#pragma unroll
            for (int q = 0; q < 4; q++) {
                a0 += u_[q] * bf2f(h_[q].x); a1 += u_[q] * bf2f(h_[q].y);
                a2 += u_[q] * bf2f(h_[q].z); a3 += u_[q] * bf2f(h_[q].w);
            }
            j += 4;
        }
        int rem = cnt - j;
        if (rem > 0) {
            int t0 = __shfl(sk, j);
            int t1 = __shfl(sk, rem > 1 ? j + 1 : j);
            int t2 = __shfl(sk, rem > 2 ? j + 2 : j);
            float u0 = __shfl(wk, j);
            float u1 = rem > 1 ? __shfl(wk, j + 1) : 0.f;
            float u2 = rem > 2 ? __shfl(wk, j + 2) : 0.f;
            ushort4 h0 = *(const ushort4*)(hb + (size_t)t0 * 1024);
            ushort4 h1 = *(const ushort4*)(hb + (size_t)t1 * 1024);
            ushort4 h2 = *(const ushort4*)(hb + (size_t)t2 * 1024);
            a0 += u0 * bf2f(h0.x) + u1 * bf2f(h1.x) + u2 * bf2f(h2.x);
            a1 += u0 * bf2f(h0.y) + u1 * bf2f(h1.y) + u2 * bf2f(h2.y);
            a2 += u0 * bf2f(h0.z) + u1 * bf2f(h1.z) + u2 * bf2f(h2.z);
            a3 += u0 * bf2f(h0.w) + u1 * bf2f(h1.w) + u2 * bf2f(h2.w);
        }
    }
    float wi = rs_i[node];
    ushort4 o;
    o.x = f2bf(a0 * wi); o.y = f2bf(a1 * wi);
    o.z = f2bf(a2 * wi); o.w = f2bf(a3 * wi);
    *(ushort4*)(hcat + (size_t)node * 1024 + 256 * (r + 1) + lane * 4) = o;
}

// ---------------------------------------------------------------------------
// bf16 MFMA GEMM, BK=64 (two 32-wide half-stages per barrier).
// C = A[bf16,ldA] @ Bt[bf16,n-major,ld=K] + bias; optional fused BN stats.
// c_bf16: 1 -> C is bf16[ldC], 0 -> C is fp32[ldC].
// ---------------------------------------------------------------------------
__global__ __launch_bounds__(256) void mfma_gemm(const unsigned short* __restrict__ A, int ldA,
                                                 const unsigned short* __restrict__ Bt,
                                                 const float* __restrict__ bias,
                                                 void* __restrict__ Cv, int ldC,
                                                 int Nstore, int K, int c_bf16,
                                                 float* __restrict__ stats) {
    __shared__ unsigned short ldsA[2][128 * 32];
    __shared__ unsigned short ldsB[2][128 * 32];
    int tid = threadIdx.x;
    int w = tid >> 6, lane = tid & 63;
    int quad = lane >> 4, lr = lane & 15;
    int bm = blockIdx.y * 128, bn = blockIdx.x * 128;
    int wm = w >> 1, wn = w & 1;
    int lrow = lane >> 2;
    int lslot = lane & 3;

    f32x4 acc[4][4];
#pragma unroll
    for (int i = 0; i < 4; i++)
#pragma unroll
        for (int j = 0; j < 4; j++) acc[i][j] = (f32x4){0.f, 0.f, 0.f, 0.f};

    for (int k0 = 0; k0 < K; k0 += 64) {
#pragma unroll
        for (int h = 0; h < 2; h++) {
            int kk0 = k0 + h * 32;
#pragma unroll
            for (int c = 0; c < 2; c++) {
                int cc = w * 2 + c;
                int rA = cc * 16 + lrow;
                int cg = lslot ^ ((rA >> 1) & 3);
                gl_lds16(A + (size_t)(bm + rA) * ldA + kk0 + cg * 8, &ldsA[h][cc * 512]);
                gl_lds16(Bt + (size_t)(bn + rA) * K + kk0 + cg * 8, &ldsB[h][cc * 512]);
            }
        }
        __syncthreads();
#pragma unroll
        for (int h = 0; h < 2; h++) {
            bf16x8 af[4], bfr[4];
#pragma unroll
            for (int i = 0; i < 4; i++) {
                int r = wm * 64 + i * 16 + lr;
                int s = quad ^ ((r >> 1) & 3);
                af[i] = *(const bf16x8*)&ldsA[h][r * 32 + s * 8];
            }
#pragma unroll
            for (int j = 0; j < 4; j++) {
                int n = wn * 64 + j * 16 + lr;
                int s = quad ^ ((n >> 1) & 3);
                bfr[j] = *(const bf16x8*)&ldsB[h][n * 32 + s * 8];
            }
#pragma unroll
            for (int i = 0; i < 4; i++)
#pragma unroll
                for (int j = 0; j < 4; j++)
                    acc[i][j] = __builtin_amdgcn_mfma_f32_16x16x32_bf16(af[i], bfr[j], acc[i][j], 0, 0, 0);
        }
        __syncthreads();
    }

    float* Cf = (float*)Cv;
    unsigned short* Cb = (unsigned short*)Cv;
#pragma unroll
    for (int j = 0; j < 4; j++) {
        int col = bn + wn * 64 + j * 16 + lr;
        if (col >= Nstore) continue;
        float bv = bias ? bias[col] : 0.f;
        float ssum = 0.f, ssq = 0.f;
#pragma unroll
        for (int i = 0; i < 4; i++) {
#pragma unroll
            for (int v = 0; v < 4; v++) {
                int row = bm + wm * 64 + i * 16 + quad * 4 + v;
                if (row < NN) {
                    float val = acc[i][j][v] + bv;
                    if (c_bf16) Cb[(size_t)row * ldC + col] = f2bf(val);
                    else        Cf[(size_t)row * ldC + col] = val;
                    ssum += val; ssq += val * val;
                }
            }
        }
        if (stats) {
            ssum += __shfl_xor(ssum, 16); ssum += __shfl_xor(ssum, 32);
            ssq  += __shfl_xor(ssq, 16);  ssq  += __shfl_xor(ssq, 32);
            if (quad == 0) {
                atomicAdd(&stats[col], ssum);
                atomicAdd(&stats[HH + col], ssq);
            }
        }
    }
}

// ---------------------------------------------------------------------------
// BN: coef precompute + vectorized apply (bf16 in, bf16 out at ld=1024)
// ---------------------------------------------------------------------------
__global__ void bn_coef(const float* __restrict__ stats, const float* __restrict__ g,
                        const float* __restrict__ b, float* __restrict__ coef, float invM) {
    int c = threadIdx.x;
    float mean = stats[c] * invM;
    float var = stats[HH + c] * invM - mean * mean;
    float inv = rsqrtf(var + 1e-5f);
    float sc = g[c] * inv;
    coef[c] = sc;
    coef[HH + c] = b[c] - mean * sc;
}

// act: 1 = relu, 2 = leaky relu (0.01)
__global__ __launch_bounds__(256) void bn_apply_v(const unsigned short* __restrict__ Z,
                                                  const float* __restrict__ coef,
                                                  unsigned short* __restrict__ out, int act) {
    int idx = blockIdx.x * blockDim.x + threadIdx.x;
    if (idx >= NN * 32) return;
    int row = idx >> 5, cg = (idx & 31) * 8;
    union { uint4 u; unsigned short s[8]; } zin, zo;
    zin.u = *(const uint4*)(Z + (size_t)row * HH + cg);
    f32x4 sc0 = *(const f32x4*)(coef + cg);
    f32x4 sc1 = *(const f32x4*)(coef + cg + 4);
    f32x4 sh0 = *(const f32x4*)(coef + HH + cg);
    f32x4 sh1 = *(const f32x4*)(coef + HH + cg + 4);
#pragma unroll
    for (int j = 0; j < 8; j++) {
        float sc = (j < 4) ? sc0[j] : sc1[j - 4];
        float sh = (j < 4) ? sh0[j] : sh1[j - 4];
        float v = bf2f(zin.s[j]) * sc + sh;
        if (act == 1) v = fmaxf(v, 0.f);
        else v = (v < 0.f) ? 0.01f * v : v;
        zo.s[j] = f2bf(v);
    }
    *(uint4*)(out + (size_t)row * 1024 + cg) = zo.u;
}

// ---------------------------------------------------------------------------
extern "C" void kernel_launch(void* const* d_in, const int* in_sizes, int n_in,
                              void* d_out, int out_size, void* d_ws, size_t ws_size,
                              hipStream_t stream) {
    const float* x        = (const float*)d_in[0];
    const int*   esrc     = (const int*)d_in[1];
    const int*   edst     = (const int*)d_in[2];
    const float* W_feat   = (const float*)d_in[3];
    const float* b_feat   = (const float*)d_in[4];
    const float* g_feat   = (const float*)d_in[5];
    const float* beta_feat= (const float*)d_in[6];
    const float* gcn_W    = (const float*)d_in[7];
    const float* gcn_b    = (const float*)d_in[8];
    const float* skip_W   = (const float*)d_in[9];
    const float* skip_b   = (const float*)d_in[10];
    const float* bn_g     = (const float*)d_in[11];
    const float* bn_b     = (const float*)d_in[12];
    const float* W_c1     = (const float*)d_in[13];
    const float* b_c1     = (const float*)d_in[14];
    const float* g_c      = (const float*)d_in[15];
    const float* beta_c   = (const float*)d_in[16];
    const float* W_c2     = (const float*)d_in[17];
    const float* b_c2     = (const float*)d_in[18];
    float* out = (float*)d_out;
    (void)in_sizes; (void)n_in; (void)out_size; (void)ws_size;

    char* w = (char*)d_ws;
    size_t off = 0;
    auto alloc = [&](size_t bytes) { void* p = w + off; off += (bytes + 255) & ~(size_t)255; return p; };
    unsigned short* hcat = (unsigned short*)alloc((size_t)MPAD * 1024 * 2);
    unsigned short* xpad = hcat;  // [MPAD][320] bf16, dead after feat GEMM
    unsigned short* c_acc = (unsigned short*)alloc((size_t)NN * HH * 2);  // bf16 pre-BN C
    float* f_stats = (float*)alloc(4 * 2 * HH * 4);   // 4 slices of [2][HH]
    float* f_coef  = (float*)alloc(2 * HH * 4);
    float* f_rs_out = (float*)alloc((size_t)RR * NN * 4);
    float* f_rs_in  = (float*)alloc((size_t)RR * NN * 4);
    int* i_cnt_out = (int*)alloc((size_t)RR * NN * 4);
    int* i_cnt_in  = (int*)alloc((size_t)RR * NN * 4);
    int* i_off     = (int*)alloc((size_t)RR * (NN + 1) * 4);
    int* i_cur     = (int*)alloc((size_t)RR * NN * 4);
    int* i_srcs    = (int*)alloc((size_t)RR * EE * 4);
    int* i_bsum    = (int*)alloc((size_t)RR * SNB * 4);
    unsigned short* Bt_feat = (unsigned short*)alloc(256 * 320 * 2);
    unsigned short* Bt_l0   = (unsigned short*)alloc(256 * 1024 * 2);
    unsigned short* Bt_l1   = (unsigned short*)alloc(256 * 1024 * 2);
    unsigned short* Bt_c1   = (unsigned short*)alloc(256 * 256 * 2);
    unsigned short* Bt_c2   = (unsigned short*)alloc(128 * 256 * 2);
    float* bias_l0 = (float*)alloc(HH * 4);
    float* bias_l1 = (float*)alloc(HH * 4);

    const float invM = 1.0f / (float)NN;
    const int RE = RR * EE;

    // --- CSR + degrees ---
    (void)hipMemsetAsync(i_cnt_out, 0, (size_t)RR * NN * 4, stream);
    (void)hipMemsetAsync(i_cnt_in, 0, (size_t)RR * NN * 4, stream);
    (void)hipMemsetAsync(f_stats, 0, 4 * 2 * HH * 4, stream);
    hist_kernel<<<cdiv_h(RE, 256), 256, 0, stream>>>(esrc, edst, i_cnt_out, i_cnt_in, RE, EE);
    rs_kernel<<<cdiv_h(RR * NN, 256), 256, 0, stream>>>(i_cnt_out, i_cnt_in, f_rs_out, f_rs_in, RR * NN);
    scan_a<<<dim3(SNB, RR), 256, 0, stream>>>(i_cnt_in, i_bsum);
    scan_b<<<1, 64, 0, stream>>>(i_bsum, i_off);
    scan_c<<<dim3(SNB, RR), 256, 0, stream>>>(i_cnt_in, i_bsum, i_off, i_cur);
    fill_kernel<<<cdiv_h(RE, 256), 256, 0, stream>>>(esrc, edst, i_cur, i_srcs, RE, EE);

    // --- weight prep (bf16, transposed) ---
    convert_x<<<MPAD, 320, 0, stream>>>(x, xpad);
    wprep_feat<<<256, 320, 0, stream>>>(W_feat, Bt_feat);
    wprep_layer<<<1024, 256, 0, stream>>>(skip_W, gcn_W, Bt_l0);
    wprep_layer<<<1024, 256, 0, stream>>>(skip_W + (size_t)HH * HH, gcn_W + (size_t)RR * HH * HH, Bt_l1);
    bias_layer<<<1, 256, 0, stream>>>(skip_b, gcn_b, bias_l0);
    bias_layer<<<1, 256, 0, stream>>>(skip_b + HH, gcn_b + (size_t)RR * HH, bias_l1);
    wprep_c1<<<256, 256, 0, stream>>>(W_c1, Bt_c1);
    wprep_c2<<<128, 256, 0, stream>>>(W_c2, Bt_c2);

    dim3 grid_H(2, MPAD / 128);
    dim3 grid_C(1, MPAD / 128);
    const int nblk_a = cdiv_h(NN * 32, 256);
    float* st0 = f_stats;
    float* st1 = f_stats + 2 * HH;
    float* st2 = f_stats + 4 * HH;
    float* st3 = f_stats + 6 * HH;

    // --- feat_reduce: h = relu(BN(x @ W_feat + b_feat)) -> hcat[:,0:256] bf16 ---
    mfma_gemm<<<grid_H, 256, 0, stream>>>(xpad, 320, Bt_feat, b_feat, c_acc, HH, HH, 320, 1, st0);
    bn_coef<<<1, 256, 0, stream>>>(st0, g_feat, beta_feat, f_coef, invM);
    bn_apply_v<<<nblk_a, 256, 0, stream>>>(c_acc, f_coef, hcat, 1);

    // --- GCN layers: one K=1024 GEMM per layer ---
    for (int l = 0; l < LL; l++) {
        agg_bf16<<<dim3(cdiv_h(NN, 4), RR), 256, 0, stream>>>(hcat, i_off, i_srcs, f_rs_out, f_rs_in);
        float* st = l ? st2 : st1;
        mfma_gemm<<<grid_H, 256, 0, stream>>>(hcat, 1024, l ? Bt_l1 : Bt_l0,
                                              l ? bias_l1 : bias_l0, c_acc, HH, HH, 1024, 1, st);
        bn_coef<<<1, 256, 0, stream>>>(st, bn_g + (size_t)l * HH, bn_b + (size_t)l * HH, f_coef, invM);
        bn_apply_v<<<nblk_a, 256, 0, stream>>>(c_acc, f_coef, hcat, 2);
    }

    // --- head ---
    mfma_gemm<<<grid_H, 256, 0, stream>>>(hcat, 1024, Bt_c1, b_c1, c_acc, HH, HH, 256, 1, st3);
    bn_coef<<<1, 256, 0, stream>>>(st3, g_c, beta_c, f_coef, invM);
    bn_apply_v<<<nblk_a, 256, 0, stream>>>(c_acc, f_coef, hcat + 256, 1);
    mfma_gemm<<<grid_C, 256, 0, stream>>>(hcat + 256, 1024, Bt_c2, b_c2, out, CC, CC, 256, 0, nullptr);
}

// Round 6
// 1233.388 us; speedup vs baseline: 3.1943x; 1.0247x over previous
//
#include <hip/hip_runtime.h>

#define NN 100000   // nodes
#define EE 500000   // edges per relation
#define RR 3        // relations
#define LL 2        // layers
#define FF 300      // input features
#define HH 256      // hidden
#define CC 23       // classes
#define MPAD 100096 // 782 * 128
#define SCHUNK 2048
#define SNB ((NN + SCHUNK - 1) / SCHUNK)   // 49

static inline int cdiv_h(int a, int b) { return (a + b - 1) / b; }

typedef __attribute__((ext_vector_type(8))) short bf16x8;
typedef __attribute__((ext_vector_type(4))) float f32x4;

__device__ inline unsigned short f2bf(float f) {
    union { float f; unsigned int u; } v; v.f = f;
    unsigned int r = v.u + 0x7fff + ((v.u >> 16) & 1);
    return (unsigned short)(r >> 16);
}
__device__ inline float bf2f(unsigned short u) {
    union { unsigned int u; float f; } v; v.u = ((unsigned int)u) << 16;
    return v.f;
}
__device__ inline void gl_lds16(const void* g, void* l) {
    __builtin_amdgcn_global_load_lds((const __attribute__((address_space(1))) unsigned int*)g,
                                     (__attribute__((address_space(3))) unsigned int*)l,
                                     16, 0, 0);
}

// ---------------------------------------------------------------------------
// CSR build
// ---------------------------------------------------------------------------
__global__ void hist_kernel(const int* __restrict__ src, const int* __restrict__ dst,
                            int* __restrict__ cnt_out, int* __restrict__ cnt_in,
                            int RE, int Eper) {
    int i = blockIdx.x * blockDim.x + threadIdx.x;
    if (i >= RE) return;
    int r = i / Eper;
    atomicAdd(&cnt_out[r * NN + src[i]], 1);
    atomicAdd(&cnt_in[r * NN + dst[i]], 1);
}

__global__ void rs_kernel(const int* __restrict__ cnt_out, const int* __restrict__ cnt_in,
                          float* __restrict__ rs_out, float* __restrict__ rs_in, int total) {
    int i = blockIdx.x * blockDim.x + threadIdx.x;
    if (i >= total) return;
    rs_out[i] = rsqrtf(fmaxf((float)cnt_out[i], 1.0f));
    rs_in[i]  = rsqrtf(fmaxf((float)cnt_in[i], 1.0f));
}

// --- 3-phase exclusive scan of in-degree counts -> CSR offsets + cursors ---
__global__ __launch_bounds__(256) void scan_a(const int* __restrict__ cnt, int* __restrict__ bsum) {
    int r = blockIdx.y, b = blockIdx.x, t = threadIdx.x;
    const int* c = cnt + (size_t)r * NN;
    int base = b * SCHUNK;
    int s = 0;
    for (int i = t; i < SCHUNK; i += 256) {
        int idx = base + i;
        if (idx < NN) s += c[idx];
    }
#pragma unroll
    for (int o = 1; o < 64; o <<= 1) s += __shfl_xor(s, o);
    __shared__ int sh[4];
    if ((t & 63) == 0) sh[t >> 6] = s;
    __syncthreads();
    if (t == 0) bsum[r * SNB + b] = sh[0] + sh[1] + sh[2] + sh[3];
}

__global__ void scan_b(int* __restrict__ bsum, int* __restrict__ offs) {
    int r = threadIdx.x;
    if (r >= RR) return;
    int* bs = bsum + r * SNB;
    int run = 0;
    for (int i = 0; i < SNB; i++) { int v = bs[i]; bs[i] = run; run += v; }
    offs[(size_t)r * (NN + 1) + NN] = run;
}

__global__ __launch_bounds__(256) void scan_c(const int* __restrict__ cnt, const int* __restrict__ bsum,
                                              int* __restrict__ offs, int* __restrict__ cur) {
    int r = blockIdx.y, b = blockIdx.x, t = threadIdx.x;
    const int* c = cnt + (size_t)r * NN;
    int base = b * SCHUNK + t * 8;
    int v[8]; int s = 0;
#pragma unroll
    for (int j = 0; j < 8; j++) {
        int idx = base + j;
        v[j] = (idx < NN) ? c[idx] : 0;
        s += v[j];
    }
    __shared__ int sh[256];
    sh[t] = s;
    __syncthreads();
    for (int d = 1; d < 256; d <<= 1) {
        int x = (t >= d) ? sh[t - d] : 0;
        __syncthreads();
        sh[t] += x;
        __syncthreads();
    }
    int run = sh[t] - s + bsum[r * SNB + b];
    int* orow = offs + (size_t)r * (NN + 1);
    int* crow = cur + (size_t)r * NN;
#pragma unroll
    for (int j = 0; j < 8; j++) {
        int idx = base + j;
        if (idx < NN) { orow[idx] = run; crow[idx] = run; }
        run += v[j];
    }
}

// Fill packed edge stream: (src, rs_out[src]) per edge, bucketed by dst.
__global__ void fill_kernel(const int* __restrict__ src, const int* __restrict__ dst,
                            const float* __restrict__ rs_out,
                            int* __restrict__ cur, int2* __restrict__ srcw,
                            int RE, int Eper) {
    int i = blockIdx.x * blockDim.x + threadIdx.x;
    if (i >= RE) return;
    int r = i / Eper;
    int d = dst[i];
    int s = src[i];
    float w = rs_out[r * NN + s];
    int pos = atomicAdd(&cur[r * NN + d], 1);
    srcw[(size_t)r * Eper + pos] = make_int2(s, __float_as_int(w));
}

// ---------------------------------------------------------------------------
// Weight prep: fp32 -> bf16, transposed to n-major [Ncols][K]
// ---------------------------------------------------------------------------
__global__ void convert_x(const float* __restrict__ x, unsigned short* __restrict__ xpad) {
    int row = blockIdx.x;
    int col = threadIdx.x;
    float v = (row < NN && col < FF) ? x[(size_t)row * FF + col] : 0.f;
    xpad[(size_t)row * 320 + col] = f2bf(v);
}

__global__ void wprep_feat(const float* __restrict__ W, unsigned short* __restrict__ Bt) {
    int n = blockIdx.x;
    int k = threadIdx.x;
    float v = (k < FF) ? W[(size_t)k * HH + n] : 0.f;
    Bt[(size_t)n * 320 + k] = f2bf(v);
}

__global__ void wprep_layer(const float* __restrict__ skipW, const float* __restrict__ gcnW,
                            unsigned short* __restrict__ Bt) {
    int idx = blockIdx.x * blockDim.x + threadIdx.x;
    int n = idx >> 10, k = idx & 1023;
    int seg = k >> 8, k2 = k & 255;
    float v = (seg == 0) ? skipW[(size_t)k2 * HH + n]
                         : gcnW[(size_t)(seg - 1) * HH * HH + (size_t)k2 * HH + n] * (1.0f / 3.0f);
    Bt[(size_t)n * 1024 + k] = f2bf(v);
}

__global__ void bias_layer(const float* __restrict__ skip_b, const float* __restrict__ gcn_b,
                           float* __restrict__ bias) {
    int t = threadIdx.x;
    bias[t] = skip_b[t] + (gcn_b[t] + gcn_b[HH + t] + gcn_b[2 * HH + t]) * (1.0f / 3.0f);
}

__global__ void wprep_c1(const float* __restrict__ W, unsigned short* __restrict__ Bt) {
    int idx = blockIdx.x * blockDim.x + threadIdx.x;
    int n = idx >> 8, k = idx & 255;
    Bt[(size_t)n * HH + k] = f2bf(W[(size_t)k * HH + n]);
}

__global__ void wprep_c2(const float* __restrict__ W, unsigned short* __restrict__ Bt) {
    int n = blockIdx.x;
    int k = threadIdx.x;
    float v = (n < CC) ? W[(size_t)k * CC + n] : 0.f;
    Bt[(size_t)n * HH + k] = f2bf(v);
}

// ---------------------------------------------------------------------------
// Aggregation (bf16): grid (NN/4, RR). One wave per dst node.
// Scalar-pipe edge stream: wave-uniform s_load of packed (src, w); gather
// address = SGPR base + lane*8 -> zero per-edge vector address math.
// ---------------------------------------------------------------------------
__global__ __launch_bounds__(256) void agg_bf16(unsigned short* __restrict__ hcat,
                                                const int* __restrict__ offs_all,
                                                const int2* __restrict__ srcw_all,
                                                const float* __restrict__ rs_in_all) {
    int r = blockIdx.y;
    const int* offs = offs_all + (size_t)r * (NN + 1);
    const int2* srcw = srcw_all + (size_t)r * EE;
    const float* rs_i = rs_in_all + (size_t)r * NN;
    int wave = threadIdx.x >> 6;
    int lane = threadIdx.x & 63;
    int node = blockIdx.x * 4 + wave;
    if (node >= NN) return;
    int s0 = __builtin_amdgcn_readfirstlane(offs[node]);
    int s1 = __builtin_amdgcn_readfirstlane(offs[node + 1]);
    int cnt = s1 - s0;
    const int2* ew = srcw + s0;
    const unsigned short* hb = hcat + lane * 4;
    float a0 = 0.f, a1 = 0.f, a2 = 0.f, a3 = 0.f;
    int k = 0;
    for (; k + 8 <= cnt; k += 8) {
        int2 e[8];
#pragma unroll
        for (int q = 0; q < 8; q++) e[q] = ew[k + q];
        ushort4 hv[8];
#pragma unroll
        for (int q = 0; q < 8; q++) hv[q] = *(const ushort4*)(hb + (size_t)e[q].x * 1024);
#pragma unroll
        for (int q = 0; q < 8; q++) {
            float u = __int_as_float(e[q].y);
            a0 += u * bf2f(hv[q].x); a1 += u * bf2f(hv[q].y);
            a2 += u * bf2f(hv[q].z); a3 += u * bf2f(hv[q].w);
        }
    }
    if (k + 4 <= cnt) {
        int2 e[4];
#pragma unroll
        for (int q = 0; q < 4; q++) e[q] = ew[k + q];
        ushort4 hv[4];
#pragma unroll
        for (int q = 0; q < 4; q++) hv[q] = *(const ushort4*)(hb + (size_t)e[q].x * 1024);
#pragma unroll
        for (int q = 0; q < 4; q++) {
            float u = __int_as_float(e[q].y);
            a0 += u * bf2f(hv[q].x); a1 += u * bf2f(hv[q].y);
            a2 += u * bf2f(hv[q].z); a3 += u * bf2f(hv[q].w);
        }
        k += 4;
    }
    int rem = cnt - k;  // 0..3
    if (rem > 0) {
        int2 e[3];
#pragma unroll
        for (int q = 0; q < 3; q++) {
            int kk = k + q; if (kk > cnt - 1) kk = cnt - 1;
            e[q] = ew[kk];
        }
        ushort4 hv[3];
#pragma unroll
        for (int q = 0; q < 3; q++) hv[q] = *(const ushort4*)(hb + (size_t)e[q].x * 1024);
        float u0 = __int_as_float(e[0].y);
        float u1 = rem > 1 ? __int_as_float(e[1].y) : 0.f;
        float u2 = rem > 2 ? __int_as_float(e[2].y) : 0.f;
        a0 += u0 * bf2f(hv[0].x) + u1 * bf2f(hv[1].x) + u2 * bf2f(hv[2].x);
        a1 += u0 * bf2f(hv[0].y) + u1 * bf2f(hv[1].y) + u2 * bf2f(hv[2].y);
        a2 += u0 * bf2f(hv[0].z) + u1 * bf2f(hv[1].z) + u2 * bf2f(hv[2].z);
        a3 += u0 * bf2f(hv[0].w) + u1 * bf2f(hv[1].w) + u2 * bf2f(hv[2].w);
    }
    float wi = rs_i[node];
    ushort4 o;
    o.x = f2bf(a0 * wi); o.y = f2bf(a1 * wi);
    o.z = f2bf(a2 * wi); o.w = f2bf(a3 * wi);
    *(ushort4*)(hcat + (size_t)node * 1024 + 256 * (r + 1) + lane * 4) = o;
}

// ---------------------------------------------------------------------------
// bf16 MFMA GEMM, BK=64 (two 32-wide half-stages per barrier).
// C = A[bf16,ldA] @ Bt[bf16,n-major,ld=K] + bias; optional fused BN stats.
// c_bf16: 1 -> C is bf16[ldC], 0 -> C is fp32[ldC].
// ---------------------------------------------------------------------------
__global__ __launch_bounds__(256) void mfma_gemm(const unsigned short* __restrict__ A, int ldA,
                                                 const unsigned short* __restrict__ Bt,
                                                 const float* __restrict__ bias,
                                                 void* __restrict__ Cv, int ldC,
                                                 int Nstore, int K, int c_bf16,
                                                 float* __restrict__ stats) {
    __shared__ unsigned short ldsA[2][128 * 32];
    __shared__ unsigned short ldsB[2][128 * 32];
    int tid = threadIdx.x;
    int w = tid >> 6, lane = tid & 63;
    int quad = lane >> 4, lr = lane & 15;
    int bm = blockIdx.y * 128, bn = blockIdx.x * 128;
    int wm = w >> 1, wn = w & 1;
    int lrow = lane >> 2;
    int lslot = lane & 3;

    f32x4 acc[4][4];
#pragma unroll
    for (int i = 0; i < 4; i++)
#pragma unroll
        for (int j = 0; j < 4; j++) acc[i][j] = (f32x4){0.f, 0.f, 0.f, 0.f};

    for (int k0 = 0; k0 < K; k0 += 64) {
#pragma unroll
        for (int h = 0; h < 2; h++) {
            int kk0 = k0 + h * 32;
#pragma unroll
            for (int c = 0; c < 2; c++) {
                int cc = w * 2 + c;
                int rA = cc * 16 + lrow;
                int cg = lslot ^ ((rA >> 1) & 3);
                gl_lds16(A + (size_t)(bm + rA) * ldA + kk0 + cg * 8, &ldsA[h][cc * 512]);
                gl_lds16(Bt + (size_t)(bn + rA) * K + kk0 + cg * 8, &ldsB[h][cc * 512]);
            }
        }
        __syncthreads();
#pragma unroll
        for (int h = 0; h < 2; h++) {
            bf16x8 af[4], bfr[4];
#pragma unroll
            for (int i = 0; i < 4; i++) {
                int r = wm * 64 + i * 16 + lr;
                int s = quad ^ ((r >> 1) & 3);
                af[i] = *(const bf16x8*)&ldsA[h][r * 32 + s * 8];
            }
#pragma unroll
            for (int j = 0; j < 4; j++) {
                int n = wn * 64 + j * 16 + lr;
                int s = quad ^ ((n >> 1) & 3);
                bfr[j] = *(const bf16x8*)&ldsB[h][n * 32 + s * 8];
            }
#pragma unroll
            for (int i = 0; i < 4; i++)
#pragma unroll
                for (int j = 0; j < 4; j++)
                    acc[i][j] = __builtin_amdgcn_mfma_f32_16x16x32_bf16(af[i], bfr[j], acc[i][j], 0, 0, 0);
        }
        __syncthreads();
    }

    float* Cf = (float*)Cv;
    unsigned short* Cb = (unsigned short*)Cv;
#pragma unroll
    for (int j = 0; j < 4; j++) {
        int col = bn + wn * 64 + j * 16 + lr;
        if (col >= Nstore) continue;
        float bv = bias ? bias[col] : 0.f;
        float ssum = 0.f, ssq = 0.f;
#pragma unroll
        for (int i = 0; i < 4; i++) {
#pragma unroll
            for (int v = 0; v < 4; v++) {
                int row = bm + wm * 64 + i * 16 + quad * 4 + v;
                if (row < NN) {
                    float val = acc[i][j][v] + bv;
                    if (c_bf16) Cb[(size_t)row * ldC + col] = f2bf(val);
                    else        Cf[(size_t)row * ldC + col] = val;
                    ssum += val; ssq += val * val;
                }
            }
        }
        if (stats) {
            ssum += __shfl_xor(ssum, 16); ssum += __shfl_xor(ssum, 32);
            ssq  += __shfl_xor(ssq, 16);  ssq  += __shfl_xor(ssq, 32);
            if (quad == 0) {
                atomicAdd(&stats[col], ssum);
                atomicAdd(&stats[HH + col], ssq);
            }
        }
    }
}

// ---------------------------------------------------------------------------
// BN: coef precompute + vectorized apply (bf16 in, bf16 out at ld=1024)
// ---------------------------------------------------------------------------
__global__ void bn_coef(const float* __restrict__ stats, const float* __restrict__ g,
                        const float* __restrict__ b, float* __restrict__ coef, float invM) {
    int c = threadIdx.x;
    float mean = stats[c] * invM;
    float var = stats[HH + c] * invM - mean * mean;
    float inv = rsqrtf(var + 1e-5f);
    float sc = g[c] * inv;
    coef[c] = sc;
    coef[HH + c] = b[c] - mean * sc;
}

// act: 1 = relu, 2 = leaky relu (0.01)
__global__ __launch_bounds__(256) void bn_apply_v(const unsigned short* __restrict__ Z,
                                                  const float* __restrict__ coef,
                                                  unsigned short* __restrict__ out, int act) {
    int idx = blockIdx.x * blockDim.x + threadIdx.x;
    if (idx >= NN * 32) return;
    int row = idx >> 5, cg = (idx & 31) * 8;
    union { uint4 u; unsigned short s[8]; } zin, zo;
    zin.u = *(const uint4*)(Z + (size_t)row * HH + cg);
    f32x4 sc0 = *(const f32x4*)(coef + cg);
    f32x4 sc1 = *(const f32x4*)(coef + cg + 4);
    f32x4 sh0 = *(const f32x4*)(coef + HH + cg);
    f32x4 sh1 = *(const f32x4*)(coef + HH + cg + 4);
#pragma unroll
    for (int j = 0; j < 8; j++) {
        float sc = (j < 4) ? sc0[j] : sc1[j - 4];
        float sh = (j < 4) ? sh0[j] : sh1[j - 4];
        float v = bf2f(zin.s[j]) * sc + sh;
        if (act == 1) v = fmaxf(v, 0.f);
        else v = (v < 0.f) ? 0.01f * v : v;
        zo.s[j] = f2bf(v);
    }
    *(uint4*)(out + (size_t)row * 1024 + cg) = zo.u;
}

// ---------------------------------------------------------------------------
extern "C" void kernel_launch(void* const* d_in, const int* in_sizes, int n_in,
                              void* d_out, int out_size, void* d_ws, size_t ws_size,
                              hipStream_t stream) {
    const float* x        = (const float*)d_in[0];
    const int*   esrc     = (const int*)d_in[1];
    const int*   edst     = (const int*)d_in[2];
    const float* W_feat   = (const float*)d_in[3];
    const float* b_feat   = (const float*)d_in[4];
    const float* g_feat   = (const float*)d_in[5];
    const float* beta_feat= (const float*)d_in[6];
    const float* gcn_W    = (const float*)d_in[7];
    const float* gcn_b    = (const float*)d_in[8];
    const float* skip_W   = (const float*)d_in[9];
    const float* skip_b   = (const float*)d_in[10];
    const float* bn_g     = (const float*)d_in[11];
    const float* bn_b     = (const float*)d_in[12];
    const float* W_c1     = (const float*)d_in[13];
    const float* b_c1     = (const float*)d_in[14];
    const float* g_c      = (const float*)d_in[15];
    const float* beta_c   = (const float*)d_in[16];
    const float* W_c2     = (const float*)d_in[17];
    const float* b_c2     = (const float*)d_in[18];
    float* out = (float*)d_out;
    (void)in_sizes; (void)n_in; (void)out_size; (void)ws_size;

    char* w = (char*)d_ws;
    size_t off = 0;
    auto alloc = [&](size_t bytes) { void* p = w + off; off += (bytes + 255) & ~(size_t)255; return p; };
    unsigned short* hcat = (unsigned short*)alloc((size_t)MPAD * 1024 * 2);
    unsigned short* xpad = hcat;  // [MPAD][320] bf16, dead after feat GEMM
    unsigned short* c_acc = (unsigned short*)alloc((size_t)NN * HH * 2);  // bf16 pre-BN C
    float* f_stats = (float*)alloc(4 * 2 * HH * 4);   // 4 slices of [2][HH]
    float* f_coef  = (float*)alloc(2 * HH * 4);
    float* f_rs_out = (float*)alloc((size_t)RR * NN * 4);
    float* f_rs_in  = (float*)alloc((size_t)RR * NN * 4);
    int* i_cnt_out = (int*)alloc((size_t)RR * NN * 4);
    int* i_cnt_in  = (int*)alloc((size_t)RR * NN * 4);
    int* i_off     = (int*)alloc((size_t)RR * (NN + 1) * 4);
    int* i_cur     = (int*)alloc((size_t)RR * NN * 4);
    int2* i_srcw   = (int2*)alloc((size_t)RR * EE * 8);
    int* i_bsum    = (int*)alloc((size_t)RR * SNB * 4);
    unsigned short* Bt_feat = (unsigned short*)alloc(256 * 320 * 2);
    unsigned short* Bt_l0   = (unsigned short*)alloc(256 * 1024 * 2);
    unsigned short* Bt_l1   = (unsigned short*)alloc(256 * 1024 * 2);
    unsigned short* Bt_c1   = (unsigned short*)alloc(256 * 256 * 2);
    unsigned short* Bt_c2   = (unsigned short*)alloc(128 * 256 * 2);
    float* bias_l0 = (float*)alloc(HH * 4);
    float* bias_l1 = (float*)alloc(HH * 4);

    const float invM = 1.0f / (float)NN;
    const int RE = RR * EE;

    // --- CSR + degrees ---
    (void)hipMemsetAsync(i_cnt_out, 0, (size_t)RR * NN * 4, stream);
    (void)hipMemsetAsync(i_cnt_in, 0, (size_t)RR * NN * 4, stream);
    (void)hipMemsetAsync(f_stats, 0, 4 * 2 * HH * 4, stream);
    hist_kernel<<<cdiv_h(RE, 256), 256, 0, stream>>>(esrc, edst, i_cnt_out, i_cnt_in, RE, EE);
    rs_kernel<<<cdiv_h(RR * NN, 256), 256, 0, stream>>>(i_cnt_out, i_cnt_in, f_rs_out, f_rs_in, RR * NN);
    scan_a<<<dim3(SNB, RR), 256, 0, stream>>>(i_cnt_in, i_bsum);
    scan_b<<<1, 64, 0, stream>>>(i_bsum, i_off);
    scan_c<<<dim3(SNB, RR), 256, 0, stream>>>(i_cnt_in, i_bsum, i_off, i_cur);
    fill_kernel<<<cdiv_h(RE, 256), 256, 0, stream>>>(esrc, edst, f_rs_out, i_cur, i_srcw, RE, EE);

    // --- weight prep (bf16, transposed) ---
    convert_x<<<MPAD, 320, 0, stream>>>(x, xpad);
    wprep_feat<<<256, 320, 0, stream>>>(W_feat, Bt_feat);
    wprep_layer<<<1024, 256, 0, stream>>>(skip_W, gcn_W, Bt_l0);
    wprep_layer<<<1024, 256, 0, stream>>>(skip_W + (size_t)HH * HH, gcn_W + (size_t)RR * HH * HH, Bt_l1);
    bias_layer<<<1, 256, 0, stream>>>(skip_b, gcn_b, bias_l0);
    bias_layer<<<1, 256, 0, stream>>>(skip_b + HH, gcn_b + (size_t)RR * HH, bias_l1);
    wprep_c1<<<256, 256, 0, stream>>>(W_c1, Bt_c1);
    wprep_c2<<<128, 256, 0, stream>>>(W_c2, Bt_c2);

    dim3 grid_H(2, MPAD / 128);
    dim3 grid_C(1, MPAD / 128);
    const int nblk_a = cdiv_h(NN * 32, 256);
    float* st0 = f_stats;
    float* st1 = f_stats + 2 * HH;
    float* st2 = f_stats + 4 * HH;
    float* st3 = f_stats + 6 * HH;

    // --- feat_reduce: h = relu(BN(x @ W_feat + b_feat)) -> hcat[:,0:256] bf16 ---
    mfma_gemm<<<grid_H, 256, 0, stream>>>(xpad, 320, Bt_feat, b_feat, c_acc, HH, HH, 320, 1, st0);
    bn_coef<<<1, 256, 0, stream>>>(st0, g_feat, beta_feat, f_coef, invM);
    bn_apply_v<<<nblk_a, 256, 0, stream>>>(c_acc, f_coef, hcat, 1);

    // --- GCN layers: one K=1024 GEMM per layer ---
    for (int l = 0; l < LL; l++) {
        agg_bf16<<<dim3(cdiv_h(NN, 4), RR), 256, 0, stream>>>(hcat, i_off, i_srcw, f_rs_in);
        float* st = l ? st2 : st1;
        mfma_gemm<<<grid_H, 256, 0, stream>>>(hcat, 1024, l ? Bt_l1 : Bt_l0,
                                              l ? bias_l1 : bias_l0, c_acc, HH, HH, 1024, 1, st);
        bn_coef<<<1, 256, 0, stream>>>(st, bn_g + (size_t)l * HH, bn_b + (size_t)l * HH, f_coef, invM);
        bn_apply_v<<<nblk_a, 256, 0, stream>>>(c_acc, f_coef, hcat, 2);
    }

    // --- head ---
    mfma_gemm<<<grid_H, 256, 0, stream>>>(hcat, 1024, Bt_c1, b_c1, c_acc, HH, HH, 256, 1, st3);
    bn_coef<<<1, 256, 0, stream>>>(st3, g_c, beta_c, f_coef, invM);
    bn_apply_v<<<nblk_a, 256, 0, stream>>>(c_acc, f_coef, hcat + 256, 1);
    mfma_gemm<<<grid_C, 256, 0, stream>>>(hcat + 256, 1024, Bt_c2, b_c2, out, CC, CC, 256, 0, nullptr);
}